// Round 4
// baseline (237.928 us; speedup 1.0000x reference)
//
#include <hip/hip_runtime.h>
#include <math.h>

// Problem constants
#define EMBED   1024
#define NHEADS  16
#define HD      64
#define BATCH   4
#define SEQ     2048
#define MROWS   (BATCH*SEQ)          // 8192
#define NKV     8388608ull           // B*H*N*64 floats per K/Q/V buffer

typedef short short8 __attribute__((ext_vector_type(8)));
typedef float floatx4 __attribute__((ext_vector_type(4)));

__device__ __forceinline__ unsigned short f2b(float f) {
    union { float f; unsigned u; } v; v.f = f;
    unsigned r = v.u + 0x7FFFu + ((v.u >> 16) & 1u);   // RN-even bf16
    return (unsigned short)(r >> 16);
}
__device__ __forceinline__ unsigned short f2b_fast(float f) {
    union { float f; unsigned u; } v; v.f = f;
    return (unsigned short)((v.u + 0x8000u) >> 16);    // round-half-up (2 ops)
}

// async global->LDS, 16B per lane; LDS dest = wave-uniform base + lane*16
#define GLDS16(gp, lp) __builtin_amdgcn_global_load_lds( \
    (const __attribute__((address_space(1))) unsigned int*)(gp), \
    (__attribute__((address_space(3))) unsigned int*)(lp), 16, 0, 0)

// ---------------------------------------------------------------------------
// Pre-pass: x fp32 -> bf16
// ---------------------------------------------------------------------------
__global__ __launch_bounds__(256) void convert_x(
    const float* __restrict__ x, unsigned short* __restrict__ x16)
{
    size_t idx = ((size_t)blockIdx.x * 256 + threadIdx.x) * 8;
    float4 a = *(const float4*)(x + idx);
    float4 b = *(const float4*)(x + idx + 4);
    ushort4 u0, u1;
    u0.x = f2b(a.x); u0.y = f2b(a.y); u0.z = f2b(a.z); u0.w = f2b(a.w);
    u1.x = f2b(b.x); u1.y = f2b(b.y); u1.z = f2b(b.z); u1.w = f2b(b.w);
    *(ushort4*)(x16 + idx) = u0;
    *(ushort4*)(x16 + idx + 4) = u1;
}

// ---------------------------------------------------------------------------
// Pre-pass: W_kqv [16][1024][192] fp32 -> Wt' [3072][1024] bf16, out-major,
// rows permuted into sections: c' = (e/64)*1024 + h*64 + (e%64)
// ---------------------------------------------------------------------------
__global__ __launch_bounds__(256) void prep_wkqv(
    const float* __restrict__ Wk, unsigned short* __restrict__ Wt)
{
    __shared__ float tile[32][33];
    const int h = blockIdx.z;
    const int k0 = blockIdx.x * 32, e0 = blockIdx.y * 32;
    const float* inh = Wk + (size_t)h * 1024 * 192;
    const int tx = threadIdx.x & 31, ty = threadIdx.x >> 5;
    #pragma unroll
    for (int i = 0; i < 4; i++)
        tile[ty + i * 8][tx] = inh[(size_t)(k0 + ty + i * 8) * 192 + e0 + tx];
    __syncthreads();
    #pragma unroll
    for (int i = 0; i < 4; i++) {
        int e = e0 + ty + i * 8;
        int cp = (e >> 6) * 1024 + h * 64 + (e & 63);
        Wt[(size_t)cp * 1024 + k0 + tx] = f2b(tile[tx][ty + i * 8]);
    }
}

// ---------------------------------------------------------------------------
// Pre-pass: tiled transpose, in fp32 [R][C] -> out bf16 [C][R] (for W_proj)
// ---------------------------------------------------------------------------
__global__ __launch_bounds__(256) void transpose_w(
    const float* __restrict__ in, unsigned short* __restrict__ outp, int R, int C)
{
    __shared__ float tile[32][33];
    const int r0 = blockIdx.x * 32, c0 = blockIdx.y * 32;
    const int tx = threadIdx.x & 31, ty = threadIdx.x >> 5;
    #pragma unroll
    for (int i = 0; i < 4; i++)
        tile[ty + i * 8][tx] = in[(size_t)(r0 + ty + i * 8) * C + c0 + tx];
    __syncthreads();
    #pragma unroll
    for (int i = 0; i < 4; i++)
        outp[(size_t)(c0 + ty + i * 8) * R + r0 + tx] = f2b(tile[tx][ty + i * 8]);
}

// ---------------------------------------------------------------------------
// Shared main loop: 128x256 output tile, 512 threads / 8 waves (2M x 4N),
// wave tile 64x64, acc[4][4]. BK=64, 2 phases per K-tile, 16 MFMA per phase.
// TRIPLE-buffered A and B (rotating pointers): iter j reads bufs j%3;
// A(j+2) staged at P1(j), B(j+2) at P2(j) -- target buffers are never the
// ones being read, so fragment reads are balanced 8/phase. Prefetch
// distance: A = 3 phases, B = 2 phases >= L2/HBM latency. Steady wait:
// vmcnt(6) once per K-tile (leaves A(j+2)[2]+B(j+2)[4] in flight).
// LDS 144KB: 3 x A[128][64] + 3 x B[256][64].
// ---------------------------------------------------------------------------
__device__ __forceinline__ void mainloop_128x256(
    const unsigned short* __restrict__ Ag,   // [8192][1024] bf16
    const unsigned short* __restrict__ Bg,   // [*][1024] bf16 out-major
    unsigned short* smem,                    // 73728 shorts (144KB)
    int row0, int col0, floatx4 (&acc)[4][4])
{
    const int t = threadIdx.x;
    const int wave = t >> 6, lane = t & 63;
    const int lr = lane & 15, quad = lane >> 4;
    const int wr = wave >> 2, wc = wave & 3;
    const int swz8 = ((lane & 7) ^ ((lane >> 3) & 7)) * 8;  // stage src swizzle
    const int c0 = (quad ^ (lr & 7)) * 8;        // kc0 fragment chunk (shorts)
    const int c1 = ((4 + quad) ^ (lr & 7)) * 8;  // kc1

    #pragma unroll
    for (int m = 0; m < 4; m++)
        #pragma unroll
        for (int n = 0; n < 4; n++) acc[m][n] = (floatx4){0.f, 0.f, 0.f, 0.f};

#define STG(G, R0, KC, L) do { \
    _Pragma("unroll") \
    for (int i_ = 0; i_ < 2; i_++) { \
        int rl_ = i_ * 64 + wave * 8 + (lane >> 3); \
        GLDS16((G) + (size_t)((R0) + rl_) * 1024 + (KC) + swz8, \
               (L) + rl_ * 64 + (lane & 7) * 8); \
    } } while (0)

    // rotating buffer pointers: aC/bC = iter j's tiles, aN2/bN2 = stage target
    unsigned short* aC  = smem;               // A bufs: 8192 shorts each
    unsigned short* aN  = smem + 8192;
    unsigned short* aN2 = smem + 16384;
    unsigned short* bC  = smem + 24576;       // B bufs: 16384 shorts each
    unsigned short* bN  = smem + 24576 + 16384;
    unsigned short* bN2 = smem + 24576 + 32768;

    // ---- prologue: A0,B0,A1,B1 in flight (12 loads)
    STG(Ag, row0,       0,  aC);              // A0 [2]
    STG(Bg, col0,       0,  bC);              // B0 h0 [2]
    STG(Bg, col0 + 128, 0,  bC + 8192);       // B0 h1 [2]
    STG(Ag, row0,       64, aN);              // A1 [2]
    STG(Bg, col0,       64, bN);              // B1 h0 [2]
    STG(Bg, col0 + 128, 64, bN + 8192);       // B1 h1 [2]
    asm volatile("s_waitcnt vmcnt(6)" ::: "memory");   // A0,B0 landed; A1,B1 in flight
    __builtin_amdgcn_s_barrier();

    #pragma unroll 2
    for (int j = 0; j < 16; ++j) {
        const unsigned short* pA = aC + (wr * 64 + lr) * 64;
        const unsigned short* pB = bC + (wc * 64 + lr) * 64;

        short8 af0[4], af1[4], b0f[4], b1f[4];

        // ---- P1: af kc0 + bf kc0 (8 reads); stage A(j+2)
        #pragma unroll
        for (int m = 0; m < 4; m++) af0[m] = *(const short8*)(pA + m * 1024 + c0);
        #pragma unroll
        for (int n = 0; n < 4; n++) b0f[n] = *(const short8*)(pB + n * 1024 + c0);
        if (j < 14) STG(Ag, row0, (j + 2) * 64, aN2);
        __builtin_amdgcn_s_barrier();
        asm volatile("s_waitcnt lgkmcnt(0)" ::: "memory");
        __builtin_amdgcn_s_setprio(1);
        #pragma unroll
        for (int m = 0; m < 4; m++)
            #pragma unroll
            for (int n = 0; n < 4; n++)
                acc[m][n] = __builtin_amdgcn_mfma_f32_16x16x32_bf16(af0[m], b0f[n], acc[m][n], 0, 0, 0);
        __builtin_amdgcn_s_setprio(0);
        __builtin_amdgcn_s_barrier();

        // ---- P2: af kc1 + bf kc1 (8 reads); stage B(j+2)
        #pragma unroll
        for (int m = 0; m < 4; m++) af1[m] = *(const short8*)(pA + m * 1024 + c1);
        #pragma unroll
        for (int n = 0; n < 4; n++) b1f[n] = *(const short8*)(pB + n * 1024 + c1);
        if (j < 14) {
            STG(Bg, col0,       (j + 2) * 64, bN2);
            STG(Bg, col0 + 128, (j + 2) * 64, bN2 + 8192);
        }
        __builtin_amdgcn_s_barrier();
        asm volatile("s_waitcnt lgkmcnt(0)" ::: "memory");
        __builtin_amdgcn_s_setprio(1);
        #pragma unroll
        for (int m = 0; m < 4; m++)
            #pragma unroll
            for (int n = 0; n < 4; n++)
                acc[m][n] = __builtin_amdgcn_mfma_f32_16x16x32_bf16(af1[m], b1f[n], acc[m][n], 0, 0, 0);
        __builtin_amdgcn_s_setprio(0);
        if (j < 14)       asm volatile("s_waitcnt vmcnt(6)" ::: "memory");  // A(j+1),B(j+1) landed
        else if (j == 14) asm volatile("s_waitcnt vmcnt(0)" ::: "memory");  // tail drain
        __builtin_amdgcn_s_barrier();

        // rotate buffers
        unsigned short* r_;
        r_ = aC; aC = aN; aN = aN2; aN2 = r_;
        r_ = bC; bC = bN; bN = bN2; bN2 = r_;
    }
#undef STG
}

// ---------------------------------------------------------------------------
// Kernel: KQV projection, 128x256 tile. grid 64x12 = 768 blocks = 3 clean
// rounds at 1 block/CU (144KB LDS).
// ---------------------------------------------------------------------------
__global__ __launch_bounds__(512, 2) void gemm_kqv(
    const unsigned short* __restrict__ A,    // x16 [8192][1024]
    const unsigned short* __restrict__ Bt,   // Wt' [3072][1024] permuted
    const float* __restrict__ bk,            // [16][192] original bias
    unsigned short* __restrict__ Kb16,
    unsigned short* __restrict__ Qb16,
    unsigned short* __restrict__ Vt16)
{
    __shared__ unsigned short smem[73728];   // 144KB

    const int mt = blockIdx.x;               // 0..63
    const int ct = blockIdx.y;               // 0..11
    const int row0 = mt * 128, col0 = ct * 256;

    floatx4 acc[4][4];
    mainloop_128x256(A, Bt, smem, row0, col0, acc);

    const int t = threadIdx.x;
    const int wave = t >> 6, lane = t & 63;
    const int lr = lane & 15, quad = lane >> 4;
    const int wr = wave >> 2, wc = wave & 3;

    // ---- epilogue: per-wave 64x64 sub-tile = one head's 64 dims
    unsigned short* W = smem + wave * 4096;  // 8KB region, wave-private
    const int sec = ct >> 2;                 // 0=K,1=Q,2=V (block-uniform)
    const int h = ((ct & 3) << 2) + wc;      // head owned by this wave
    const int bidx = row0 >> 11;
    const int rbase = (row0 & 2047) + wr * 64;

    float bias[4];
    #pragma unroll
    for (int n = 0; n < 4; n++) bias[n] = bk[h * 192 + sec * 64 + n * 16 + lr];

    if (sec < 2) {
        const float scl = (sec == 1) ? (0.125f * 1.44269504089f) : 1.0f;
        #pragma unroll
        for (int m = 0; m < 4; m++)
            #pragma unroll
            for (int n = 0; n < 4; n++) {
                int es = (n * 16 + lr) ^ (quad << 4);   // bank swizzle
                #pragma unroll
                for (int r = 0; r < 4; r++)
                    W[(m * 16 + quad * 4 + r) * 64 + es] = f2b((acc[m][n][r] + bias[n]) * scl);
            }
        __syncthreads();
        unsigned short* dst = ((sec == 0) ? Kb16 : Qb16)
                              + ((size_t)(bidx * 16 + h) * 2048 + rbase) * 64;
        const int rrow = lane >> 3, chunk = lane & 7;
        #pragma unroll
        for (int p = 0; p < 8; p++) {
            int row = p * 8 + rrow;
            int ch = chunk ^ (((row >> 2) & 3) << 1);   // de-swizzle
            *(float4*)(dst + (size_t)row * 64 + chunk * 8) =
                *(const float4*)(W + row * 64 + ch * 8);
        }
    } else {
        #pragma unroll
        for (int m = 0; m < 4; m++)
            #pragma unroll
            for (int n = 0; n < 4; n++) {
                int e = n * 16 + lr;
                ushort4 pk;
                pk.x = f2b(acc[m][n][0] + bias[n]);
                pk.y = f2b(acc[m][n][1] + bias[n]);
                pk.z = f2b(acc[m][n][2] + bias[n]);
                pk.w = f2b(acc[m][n][3] + bias[n]);
                int mp = m ^ (lr & 3);                  // bank swizzle on m-bits
                *(ushort4*)(W + e * 64 + mp * 16 + quad * 4) = pk;
            }
        __syncthreads();
        unsigned short* dstV = Vt16 + (size_t)(bidx * 16 + h) * 64 * 2048 + rbase;
        const int ev = lane >> 3, chunkR = lane & 7;
        #pragma unroll
        for (int p = 0; p < 8; p++) {
            int e = p * 8 + ev;
            int ch = chunkR ^ ((e & 3) << 1);           // de-swizzle
            *(float4*)(dstV + (size_t)e * 2048 + chunkR * 8) =
                *(const float4*)(W + e * 64 + ch * 8);
        }
    }
}

// ---------------------------------------------------------------------------
// Kernel: flash-style causal attention, bf16 MFMA. (unchanged this round)
// ---------------------------------------------------------------------------
__global__ __launch_bounds__(256, 2) void attn_mfma(
    const unsigned short* __restrict__ Kb,   // [bh][2048][64]
    const unsigned short* __restrict__ Qb,   // [bh][2048][64], pre-scaled
    const unsigned short* __restrict__ Vt,   // [bh][64][2048]
    unsigned short* __restrict__ sa)         // [8192][1024] bf16
{
    const int bh = blockIdx.x;               // 0..63  (XCD = bh & 7)
    const int bx = blockIdx.y;               // 0..7
    const int b = bh >> 4, h = bh & 15;
    const int wave = threadIdx.x >> 6;
    const int lane = threadIdx.x & 63;
    const int lr = lane & 15, quad = lane >> 4;
    const int qt_[2] = {bx, 15 - bx};        // 128-row tile indices

    __shared__ unsigned short Ks[2][64 * 64];  // double-buffered, swizzled
    __shared__ unsigned short Vs[2][64 * 64];
    __shared__ unsigned short Ps[4][2][16 * 72]; // per-wave per-strip P

    const unsigned short* Kbh = Kb + (size_t)bh * 2048 * 64;
    const unsigned short* Vbh = Vt + (size_t)bh * 64 * 2048;
    const unsigned short* Qbh = Qb + (size_t)bh * 2048 * 64;

    // Q A-fragments: 2 tiles x 2 strips x 2 K-chunks
    short8 qf[2][2][2];
    #pragma unroll
    for (int tt = 0; tt < 2; tt++)
        #pragma unroll
        for (int s = 0; s < 2; s++) {
            const unsigned short* qp = Qbh +
                (size_t)(qt_[tt] * 128 + wave * 32 + s * 16 + lr) * 64 + quad * 8;
            qf[tt][s][0] = *(const short8*)(qp);
            qf[tt][s][1] = *(const short8*)(qp + 32);
        }

    floatx4 O[2][2][4];
    float ls[2][2][4];
    #pragma unroll
    for (int tt = 0; tt < 2; tt++)
        #pragma unroll
        for (int s = 0; s < 2; s++) {
            #pragma unroll
            for (int d = 0; d < 4; d++) O[tt][s][d] = (floatx4){0.f, 0.f, 0.f, 0.f};
            #pragma unroll
            for (int r = 0; r < 4; r++) ls[tt][s][r] = 0.f;
        }

    const int r_local = lane >> 3, cc = lane & 7;
    const int swz = cc ^ r_local;            // data chunk this lane stages
    const int whalf = wave >> 1;             // 0: rows 0..63, 1: rows 64..127

    // stage K/V tile kt into buffer bsel (4 GLDS per wave)
#define STAGE_KV(KT, BSEL) do { \
    const int k0_ = (KT) * 64; \
    _Pragma("unroll") \
    for (int j_ = 0; j_ < 2; j_++) { \
        int R_ = wave * 16 + j_ * 8 + r_local; \
        GLDS16(Kbh + (size_t)(k0_ + R_) * 64 + swz * 8, \
               &Ks[BSEL][0] + (wave * 16 + j_ * 8) * 64 + lane * 8); \
        GLDS16(Vbh + (size_t)R_ * 2048 + k0_ + swz * 8, \
               &Vs[BSEL][0] + (wave * 16 + j_ * 8) * 64 + lane * 8); \
    } } while (0)

    const int ktmax = 2 * qt_[1] + 1;

    // prologue: stage kt=0 into buffer 0; wait (also covers qf loads)
    STAGE_KV(0, 0);
    asm volatile("s_waitcnt vmcnt(0)" ::: "memory");
    __builtin_amdgcn_s_barrier();

    for (int kt = 0; kt <= ktmax; kt++) {
        const int buf = kt & 1;
        const unsigned short* Ksb = &Ks[buf][0];
        const unsigned short* Vsb = &Vs[buf][0];
        const int k0 = kt * 64;

        // stage next tile into the other buffer (its readers finished at the
        // barrier that closed iteration kt-1)
        if (kt < ktmax) {
            if (buf) STAGE_KV(kt + 1, 0);
            else     STAGE_KV(kt + 1, 1);
        }

        #pragma unroll
        for (int tt = 0; tt < 2; tt++) {
            const int qt2 = qt_[tt];
            const int lim = 2 * qt2 + whalf;  // wave-uniform last active kt
            if (kt > lim) continue;

            // S = Q K^T, kf shared across both strips
            floatx4 S[2][4];
            #pragma unroll
            for (int s = 0; s < 2; s++)
                #pragma unroll
                for (int a = 0; a < 4; a++) S[s][a] = (floatx4){0.f, 0.f, 0.f, 0.f};
            #pragma unroll
            for (int c = 0; c < 2; c++)
                #pragma unroll
                for (int a = 0; a < 4; a++) {
                    int R = a * 16 + lr;
                    short8 kf = *(const short8*)(Ksb + R * 64 + (((c * 4 + quad) ^ (lr & 7)) * 8));
                    #pragma unroll
                    for (int s = 0; s < 2; s++)
                        S[s][a] = __builtin_amdgcn_mfma_f32_16x16x32_bf16(qf[tt][s][c], kf, S[s][a], 0, 0, 0);
                }

            // causal mask, only on this wave's final active iteration
            if (kt == lim) {
                #pragma unroll
                for (int s = 0; s < 2; s++)
                    #pragma unroll
                    for (int a = 0; a < 4; a++) {
                        int col = k0 + a * 16 + lr;
                        #pragma unroll
                        for (int r = 0; r < 4; r++) {
                            int grow = qt2 * 128 + wave * 32 + s * 16 + quad * 4 + r;
                            if (col > grow) S[s][a][r] = -INFINITY;
                        }
                    }
            }

            // P = 2^s, accumulate row-sums, bf16 into per-strip LDS buffers
            #pragma unroll
            for (int s = 0; s < 2; s++)
                #pragma unroll
                for (int a = 0; a < 4; a++)
                    #pragma unroll
                    for (int r = 0; r < 4; r++) {
                        float p = __builtin_amdgcn_exp2f(S[s][a][r]);
                        ls[tt][s][r] += p;
                        Ps[wave][s][(quad * 4 + r) * 72 + a * 16 + lr] = f2b_fast(p);
                    }

            // P A-fragments (both strips live for vf sharing)
            short8 pa[2][2];
            #pragma unroll
            for (int s = 0; s < 2; s++)
                #pragma unroll
                for (int c = 0; c < 2; c++)
                    pa[s][c] = *(const short8*)(Ps[wave][s] + lr * 72 + c * 32 + quad * 8);

            // O += P V, vf shared across both strips
            #pragma unroll
            for (int c = 0; c < 2; c++)
                #pragma unroll
                for (int d = 0; d < 4; d++) {
                    int R = d * 16 + lr;
                    short8 vf = *(const short8*)(Vsb + R * 64 + (((c * 4 + quad) ^ (lr & 7)) * 8));
                    #pragma unroll
                    for (int s = 0; s < 2; s++)
                        O[tt][s][d] = __builtin_amdgcn_mfma_f32_16x16x32_bf16(pa[s][c], vf, O[tt][s][d], 0, 0, 0);
                }
        }

        // next tile landed + all waves done reading this buffer
        asm volatile("s_waitcnt vmcnt(0)" ::: "memory");
        __builtin_amdgcn_s_barrier();
    }
#undef STAGE_KV

    // final row-sum reduction (over lr lanes) + normalize + store
    #pragma unroll
    for (int tt = 0; tt < 2; tt++)
        #pragma unroll
        for (int s = 0; s < 2; s++)
            #pragma unroll
            for (int r = 0; r < 4; r++) {
                float sm = ls[tt][s][r];
                sm += __shfl_xor(sm, 1);
                sm += __shfl_xor(sm, 2);
                sm += __shfl_xor(sm, 4);
                sm += __shfl_xor(sm, 8);
                float inv = 1.0f / sm;
                size_t base = ((size_t)(b * 2048 + qt_[tt] * 128 + wave * 32 + s * 16 + quad * 4 + r)) * 1024
                              + h * 64 + lr;
                #pragma unroll
                for (int d = 0; d < 4; d++)
                    sa[base + d * 16] = f2b(O[tt][s][d][r] * inv);
            }
}

// ---------------------------------------------------------------------------
// Kernel: output projection, 128x256 tile, same pipelined main loop.
// grid 64x4 = 256 blocks = 1 clean round. Direct fp32 stores + bias.
// ---------------------------------------------------------------------------
__global__ __launch_bounds__(512, 2) void gemm_proj(
    const unsigned short* __restrict__ A,    // sa16 [8192][1024]
    const unsigned short* __restrict__ Bt,   // Wpt [1024][1024] out-major
    const float* __restrict__ bp,            // [1024]
    float* __restrict__ out)                 // [8192][1024] fp32
{
    __shared__ unsigned short smem[73728];   // 144KB

    const int mt = blockIdx.x;               // 0..63
    const int ct = blockIdx.y;               // 0..3
    const int row0 = mt * 128, col0 = ct * 256;

    floatx4 acc[4][4];
    mainloop_128x256(A, Bt, smem, row0, col0, acc);

    const int t = threadIdx.x;
    const int lane = t & 63, wave = t >> 6;
    const int lr = lane & 15, quad = lane >> 4;
    const int wr = wave >> 2, wc = wave & 3;

    float bias[4]; int cols[4];
    #pragma unroll
    for (int n = 0; n < 4; n++) {
        cols[n] = col0 + wc * 64 + n * 16 + lr;
        bias[n] = bp[cols[n]];
    }
    #pragma unroll
    for (int a = 0; a < 4; a++) {
        #pragma unroll
        for (int n = 0; n < 4; n++) {
            #pragma unroll
            for (int r = 0; r < 4; r++) {
                int m = row0 + wr * 64 + a * 16 + quad * 4 + r;
                out[(size_t)m * 1024 + cols[n]] = acc[a][n][r] + bias[n];
            }
        }
    }
}

extern "C" void kernel_launch(void* const* d_in, const int* in_sizes, int n_in,
                              void* d_out, int out_size, void* d_ws, size_t ws_size,
                              hipStream_t stream) {
    const float* x  = (const float*)d_in[0];   // [4,2048,1024]
    const float* Wk = (const float*)d_in[1];   // [16,1024,192]
    const float* bk = (const float*)d_in[2];   // [16,192]
    const float* Wp = (const float*)d_in[3];   // [1024,1024]
    const float* bp = (const float*)d_in[4];   // [1024]
    float* out = (float*)d_out;                // [4,2048,1024]

    unsigned short* Kb16 = (unsigned short*)d_ws;   // [bh][2048][64]
    unsigned short* Qb16 = Kb16 + NKV;              // pre-scaled by 0.125*log2e
    unsigned short* Vt16 = Qb16 + NKV;              // [bh][64][2048]
    unsigned short* sa16 = Vt16 + NKV;              // [8192][1024]
    unsigned short* x16  = sa16 + 8388608ull;       // [8192][1024]
    unsigned short* Wt   = x16  + 8388608ull;       // [3072][1024] permuted
    unsigned short* Wpt  = Wt   + 3145728ull;       // [1024][1024]

    convert_x<<<4096, 256, 0, stream>>>(x, x16);
    prep_wkqv<<<dim3(32, 6, 16), 256, 0, stream>>>(Wk, Wt);
    transpose_w<<<dim3(32, 32, 1), 256, 0, stream>>>(Wp, Wpt, 1024, 1024);
    gemm_kqv<<<dim3(64, 12), 512, 0, stream>>>(x16, Wt, bk, Kb16, Qb16, Vt16);
    attn_mfma<<<dim3(64, 8), 256, 0, stream>>>(Kb16, Qb16, Vt16, sa16);
    gemm_proj<<<dim3(64, 4), 512, 0, stream>>>(sa16, Wpt, bp, out);
}

// Round 5
// 235.657 us; speedup vs baseline: 1.0096x; 1.0096x over previous
//
#include <hip/hip_runtime.h>
#include <math.h>

// Problem constants
#define EMBED   1024
#define NHEADS  16
#define HD      64
#define BATCH   4
#define SEQ     2048
#define MROWS   (BATCH*SEQ)          // 8192
#define NKV     8388608ull           // B*H*N*64 floats per K/Q/V buffer

typedef short short8 __attribute__((ext_vector_type(8)));
typedef float floatx4 __attribute__((ext_vector_type(4)));

__device__ __forceinline__ unsigned short f2b(float f) {
    union { float f; unsigned u; } v; v.f = f;
    unsigned r = v.u + 0x7FFFu + ((v.u >> 16) & 1u);   // RN-even bf16
    return (unsigned short)(r >> 16);
}
__device__ __forceinline__ unsigned short f2b_fast(float f) {
    union { float f; unsigned u; } v; v.f = f;
    return (unsigned short)((v.u + 0x8000u) >> 16);    // round-half-up (2 ops)
}

// async global->LDS, 16B per lane; LDS dest = wave-uniform base + lane*16
#define GLDS16(gp, lp) __builtin_amdgcn_global_load_lds( \
    (const __attribute__((address_space(1))) unsigned int*)(gp), \
    (__attribute__((address_space(3))) unsigned int*)(lp), 16, 0, 0)

// ---------------------------------------------------------------------------
// Pre-pass: x fp32 -> bf16
// ---------------------------------------------------------------------------
__global__ __launch_bounds__(256) void convert_x(
    const float* __restrict__ x, unsigned short* __restrict__ x16)
{
    size_t idx = ((size_t)blockIdx.x * 256 + threadIdx.x) * 8;
    float4 a = *(const float4*)(x + idx);
    float4 b = *(const float4*)(x + idx + 4);
    ushort4 u0, u1;
    u0.x = f2b(a.x); u0.y = f2b(a.y); u0.z = f2b(a.z); u0.w = f2b(a.w);
    u1.x = f2b(b.x); u1.y = f2b(b.y); u1.z = f2b(b.z); u1.w = f2b(b.w);
    *(ushort4*)(x16 + idx) = u0;
    *(ushort4*)(x16 + idx + 4) = u1;
}

// ---------------------------------------------------------------------------
// Pre-pass: W_kqv [16][1024][192] fp32 -> Wt' [3072][1024] bf16, out-major,
// rows permuted into sections: c' = (e/64)*1024 + h*64 + (e%64)
// ---------------------------------------------------------------------------
__global__ __launch_bounds__(256) void prep_wkqv(
    const float* __restrict__ Wk, unsigned short* __restrict__ Wt)
{
    __shared__ float tile[32][33];
    const int h = blockIdx.z;
    const int k0 = blockIdx.x * 32, e0 = blockIdx.y * 32;
    const float* inh = Wk + (size_t)h * 1024 * 192;
    const int tx = threadIdx.x & 31, ty = threadIdx.x >> 5;
    #pragma unroll
    for (int i = 0; i < 4; i++)
        tile[ty + i * 8][tx] = inh[(size_t)(k0 + ty + i * 8) * 192 + e0 + tx];
    __syncthreads();
    #pragma unroll
    for (int i = 0; i < 4; i++) {
        int e = e0 + ty + i * 8;
        int cp = (e >> 6) * 1024 + h * 64 + (e & 63);
        Wt[(size_t)cp * 1024 + k0 + tx] = f2b(tile[tx][ty + i * 8]);
    }
}

// ---------------------------------------------------------------------------
// Pre-pass: tiled transpose, in fp32 [R][C] -> out bf16 [C][R] (for W_proj)
// ---------------------------------------------------------------------------
__global__ __launch_bounds__(256) void transpose_w(
    const float* __restrict__ in, unsigned short* __restrict__ outp, int R, int C)
{
    __shared__ float tile[32][33];
    const int r0 = blockIdx.x * 32, c0 = blockIdx.y * 32;
    const int tx = threadIdx.x & 31, ty = threadIdx.x >> 5;
    #pragma unroll
    for (int i = 0; i < 4; i++)
        tile[ty + i * 8][tx] = in[(size_t)(r0 + ty + i * 8) * C + c0 + tx];
    __syncthreads();
    #pragma unroll
    for (int i = 0; i < 4; i++)
        outp[(size_t)(c0 + ty + i * 8) * R + r0 + tx] = f2b(tile[tx][ty + i * 8]);
}

// ---------------------------------------------------------------------------
// Shared main loop: 128x256 output tile, 512 threads / 8 waves (2M x 4N),
// wave tile 64x64, acc[4][4]. BK=64. TRIPLE-buffered A and B, ONE barrier
// per K-tile: with triple buffering, iter j stages slot (j+2)%3 whose last
// readers (iter j-1) completed their ds_reads before the end-of-(j-1)
// barrier (each wave's lgkmcnt(0) precedes its barrier arrival). Per iter:
// {16 ds_read; stage A(j+2)+B(j+2); lgkmcnt(0); setprio(1); 32 MFMA;
// setprio(0); vmcnt(6); barrier}. Manual 3x unroll = static buffer slots.
// LDS 144KB: 3 x A[128][64] + 3 x B[256][64].
// ---------------------------------------------------------------------------
__device__ __forceinline__ void mainloop_128x256(
    const unsigned short* __restrict__ Ag,   // [8192][1024] bf16
    const unsigned short* __restrict__ Bg,   // [*][1024] bf16 out-major
    unsigned short* smem,                    // 73728 shorts (144KB)
    int row0, int col0, floatx4 (&acc)[4][4])
{
    const int t = threadIdx.x;
    const int wave = t >> 6, lane = t & 63;
    const int lr = lane & 15, quad = lane >> 4;
    const int wr = wave >> 2, wc = wave & 3;
    const int swz8 = ((lane & 7) ^ ((lane >> 3) & 7)) * 8;  // stage src swizzle
    const int c0 = (quad ^ (lr & 7)) * 8;        // kc0 fragment chunk (shorts)
    const int c1 = ((4 + quad) ^ (lr & 7)) * 8;  // kc1

    #pragma unroll
    for (int m = 0; m < 4; m++)
        #pragma unroll
        for (int n = 0; n < 4; n++) acc[m][n] = (floatx4){0.f, 0.f, 0.f, 0.f};

#define STG(G, R0, KC, L) do { \
    _Pragma("unroll") \
    for (int i_ = 0; i_ < 2; i_++) { \
        int rl_ = i_ * 64 + wave * 8 + (lane >> 3); \
        GLDS16((G) + (size_t)((R0) + rl_) * 1024 + (KC) + swz8, \
               (L) + rl_ * 64 + (lane & 7) * 8); \
    } } while (0)

    // static buffer slots
    unsigned short* const a0 = smem;                 // A: 8192 shorts each
    unsigned short* const a1 = smem + 8192;
    unsigned short* const a2 = smem + 16384;
    unsigned short* const b0 = smem + 24576;         // B: 16384 shorts each
    unsigned short* const b1 = smem + 24576 + 16384;
    unsigned short* const b2 = smem + 24576 + 32768;

    // one K-tile: read slot AR/BR, stage K-tile J+2 into AT/BT
#define KTILE(J, AR, BR, AT, BT) do { \
    const unsigned short* pA_ = (AR) + (wr * 64 + lr) * 64; \
    const unsigned short* pB_ = (BR) + (wc * 64 + lr) * 64; \
    short8 af0[4], af1[4], b0f[4], b1f[4]; \
    _Pragma("unroll") \
    for (int m = 0; m < 4; m++) { \
        af0[m] = *(const short8*)(pA_ + m * 1024 + c0); \
        af1[m] = *(const short8*)(pA_ + m * 1024 + c1); \
    } \
    _Pragma("unroll") \
    for (int n = 0; n < 4; n++) { \
        b0f[n] = *(const short8*)(pB_ + n * 1024 + c0); \
        b1f[n] = *(const short8*)(pB_ + n * 1024 + c1); \
    } \
    if ((J) < 14) { \
        STG(Ag, row0,       ((J) + 2) * 64, (AT)); \
        STG(Bg, col0,       ((J) + 2) * 64, (BT)); \
        STG(Bg, col0 + 128, ((J) + 2) * 64, (BT) + 8192); \
    } \
    asm volatile("s_waitcnt lgkmcnt(0)" ::: "memory"); \
    __builtin_amdgcn_s_setprio(1); \
    _Pragma("unroll") \
    for (int m = 0; m < 4; m++) \
        _Pragma("unroll") \
        for (int n = 0; n < 4; n++) \
            acc[m][n] = __builtin_amdgcn_mfma_f32_16x16x32_bf16(af0[m], b0f[n], acc[m][n], 0, 0, 0); \
    _Pragma("unroll") \
    for (int m = 0; m < 4; m++) \
        _Pragma("unroll") \
        for (int n = 0; n < 4; n++) \
            acc[m][n] = __builtin_amdgcn_mfma_f32_16x16x32_bf16(af1[m], b1f[n], acc[m][n], 0, 0, 0); \
    __builtin_amdgcn_s_setprio(0); \
    if ((J) < 14)       { asm volatile("s_waitcnt vmcnt(6)" ::: "memory"); } \
    else if ((J) == 14) { asm volatile("s_waitcnt vmcnt(0)" ::: "memory"); } \
    __builtin_amdgcn_s_barrier(); \
} while (0)

    // ---- prologue: A0,B0,A1,B1 in flight (12 loads)
    STG(Ag, row0,       0,  a0);
    STG(Bg, col0,       0,  b0);
    STG(Bg, col0 + 128, 0,  b0 + 8192);
    STG(Ag, row0,       64, a1);
    STG(Bg, col0,       64, b1);
    STG(Bg, col0 + 128, 64, b1 + 8192);
    asm volatile("s_waitcnt vmcnt(6)" ::: "memory");   // A0,B0 landed; A1,B1 in flight
    __builtin_amdgcn_s_barrier();

    // 16 K-tiles: 5 x 3 + 1, static slot rotation (read j%3, stage (j+2)%3)
    for (int j0 = 0; j0 < 15; j0 += 3) {
        KTILE(j0,     a0, b0, a2, b2);
        KTILE(j0 + 1, a1, b1, a0, b0);
        KTILE(j0 + 2, a2, b2, a1, b1);
    }
    KTILE(15, a0, b0, a2, b2);
#undef KTILE
#undef STG
}

// ---------------------------------------------------------------------------
// Kernel: KQV projection, 128x256 tile. grid 64x12 = 768 blocks = 3 clean
// rounds at 1 block/CU (144KB LDS).
// ---------------------------------------------------------------------------
__global__ __launch_bounds__(512, 2) void gemm_kqv(
    const unsigned short* __restrict__ A,    // x16 [8192][1024]
    const unsigned short* __restrict__ Bt,   // Wt' [3072][1024] permuted
    const float* __restrict__ bk,            // [16][192] original bias
    unsigned short* __restrict__ Kb16,
    unsigned short* __restrict__ Qb16,
    unsigned short* __restrict__ Vt16)
{
    __shared__ unsigned short smem[73728];   // 144KB

    const int mt = blockIdx.x;               // 0..63
    const int ct = blockIdx.y;               // 0..11
    const int row0 = mt * 128, col0 = ct * 256;

    floatx4 acc[4][4];
    mainloop_128x256(A, Bt, smem, row0, col0, acc);

    const int t = threadIdx.x;
    const int wave = t >> 6, lane = t & 63;
    const int lr = lane & 15, quad = lane >> 4;
    const int wr = wave >> 2, wc = wave & 3;

    // ---- epilogue: per-wave 64x64 sub-tile = one head's 64 dims
    unsigned short* W = smem + wave * 4096;  // 8KB region, wave-private
    const int sec = ct >> 2;                 // 0=K,1=Q,2=V (block-uniform)
    const int h = ((ct & 3) << 2) + wc;      // head owned by this wave
    const int bidx = row0 >> 11;
    const int rbase = (row0 & 2047) + wr * 64;

    float bias[4];
    #pragma unroll
    for (int n = 0; n < 4; n++) bias[n] = bk[h * 192 + sec * 64 + n * 16 + lr];

    if (sec < 2) {
        const float scl = (sec == 1) ? (0.125f * 1.44269504089f) : 1.0f;
        #pragma unroll
        for (int m = 0; m < 4; m++)
            #pragma unroll
            for (int n = 0; n < 4; n++) {
                int es = (n * 16 + lr) ^ (quad << 4);   // bank swizzle
                #pragma unroll
                for (int r = 0; r < 4; r++)
                    W[(m * 16 + quad * 4 + r) * 64 + es] = f2b((acc[m][n][r] + bias[n]) * scl);
            }
        __syncthreads();
        unsigned short* dst = ((sec == 0) ? Kb16 : Qb16)
                              + ((size_t)(bidx * 16 + h) * 2048 + rbase) * 64;
        const int rrow = lane >> 3, chunk = lane & 7;
        #pragma unroll
        for (int p = 0; p < 8; p++) {
            int row = p * 8 + rrow;
            int ch = chunk ^ (((row >> 2) & 3) << 1);   // de-swizzle
            *(float4*)(dst + (size_t)row * 64 + chunk * 8) =
                *(const float4*)(W + row * 64 + ch * 8);
        }
    } else {
        #pragma unroll
        for (int m = 0; m < 4; m++)
            #pragma unroll
            for (int n = 0; n < 4; n++) {
                int e = n * 16 + lr;
                ushort4 pk;
                pk.x = f2b(acc[m][n][0] + bias[n]);
                pk.y = f2b(acc[m][n][1] + bias[n]);
                pk.z = f2b(acc[m][n][2] + bias[n]);
                pk.w = f2b(acc[m][n][3] + bias[n]);
                int mp = m ^ (lr & 3);                  // bank swizzle on m-bits
                *(ushort4*)(W + e * 64 + mp * 16 + quad * 4) = pk;
            }
        __syncthreads();
        unsigned short* dstV = Vt16 + (size_t)(bidx * 16 + h) * 64 * 2048 + rbase;
        const int ev = lane >> 3, chunkR = lane & 7;
        #pragma unroll
        for (int p = 0; p < 8; p++) {
            int e = p * 8 + ev;
            int ch = chunkR ^ ((e & 3) << 1);           // de-swizzle
            *(float4*)(dstV + (size_t)e * 2048 + chunkR * 8) =
                *(const float4*)(W + e * 64 + ch * 8);
        }
    }
}

// ---------------------------------------------------------------------------
// Kernel: flash-style causal attention, bf16 MFMA. (unchanged this round)
// ---------------------------------------------------------------------------
__global__ __launch_bounds__(256, 2) void attn_mfma(
    const unsigned short* __restrict__ Kb,   // [bh][2048][64]
    const unsigned short* __restrict__ Qb,   // [bh][2048][64], pre-scaled
    const unsigned short* __restrict__ Vt,   // [bh][64][2048]
    unsigned short* __restrict__ sa)         // [8192][1024] bf16
{
    const int bh = blockIdx.x;               // 0..63  (XCD = bh & 7)
    const int bx = blockIdx.y;               // 0..7
    const int b = bh >> 4, h = bh & 15;
    const int wave = threadIdx.x >> 6;
    const int lane = threadIdx.x & 63;
    const int lr = lane & 15, quad = lane >> 4;
    const int qt_[2] = {bx, 15 - bx};        // 128-row tile indices

    __shared__ unsigned short Ks[2][64 * 64];  // double-buffered, swizzled
    __shared__ unsigned short Vs[2][64 * 64];
    __shared__ unsigned short Ps[4][2][16 * 72]; // per-wave per-strip P

    const unsigned short* Kbh = Kb + (size_t)bh * 2048 * 64;
    const unsigned short* Vbh = Vt + (size_t)bh * 64 * 2048;
    const unsigned short* Qbh = Qb + (size_t)bh * 2048 * 64;

    // Q A-fragments: 2 tiles x 2 strips x 2 K-chunks
    short8 qf[2][2][2];
    #pragma unroll
    for (int tt = 0; tt < 2; tt++)
        #pragma unroll
        for (int s = 0; s < 2; s++) {
            const unsigned short* qp = Qbh +
                (size_t)(qt_[tt] * 128 + wave * 32 + s * 16 + lr) * 64 + quad * 8;
            qf[tt][s][0] = *(const short8*)(qp);
            qf[tt][s][1] = *(const short8*)(qp + 32);
        }

    floatx4 O[2][2][4];
    float ls[2][2][4];
    #pragma unroll
    for (int tt = 0; tt < 2; tt++)
        #pragma unroll
        for (int s = 0; s < 2; s++) {
            #pragma unroll
            for (int d = 0; d < 4; d++) O[tt][s][d] = (floatx4){0.f, 0.f, 0.f, 0.f};
            #pragma unroll
            for (int r = 0; r < 4; r++) ls[tt][s][r] = 0.f;
        }

    const int r_local = lane >> 3, cc = lane & 7;
    const int swz = cc ^ r_local;            // data chunk this lane stages
    const int whalf = wave >> 1;             // 0: rows 0..63, 1: rows 64..127

    // stage K/V tile kt into buffer bsel (4 GLDS per wave)
#define STAGE_KV(KT, BSEL) do { \
    const int k0_ = (KT) * 64; \
    _Pragma("unroll") \
    for (int j_ = 0; j_ < 2; j_++) { \
        int R_ = wave * 16 + j_ * 8 + r_local; \
        GLDS16(Kbh + (size_t)(k0_ + R_) * 64 + swz * 8, \
               &Ks[BSEL][0] + (wave * 16 + j_ * 8) * 64 + lane * 8); \
        GLDS16(Vbh + (size_t)R_ * 2048 + k0_ + swz * 8, \
               &Vs[BSEL][0] + (wave * 16 + j_ * 8) * 64 + lane * 8); \
    } } while (0)

    const int ktmax = 2 * qt_[1] + 1;

    // prologue: stage kt=0 into buffer 0; wait (also covers qf loads)
    STAGE_KV(0, 0);
    asm volatile("s_waitcnt vmcnt(0)" ::: "memory");
    __builtin_amdgcn_s_barrier();

    for (int kt = 0; kt <= ktmax; kt++) {
        const int buf = kt & 1;
        const unsigned short* Ksb = &Ks[buf][0];
        const unsigned short* Vsb = &Vs[buf][0];
        const int k0 = kt * 64;

        // stage next tile into the other buffer (its readers finished at the
        // barrier that closed iteration kt-1)
        if (kt < ktmax) {
            if (buf) STAGE_KV(kt + 1, 0);
            else     STAGE_KV(kt + 1, 1);
        }

        #pragma unroll
        for (int tt = 0; tt < 2; tt++) {
            const int qt2 = qt_[tt];
            const int lim = 2 * qt2 + whalf;  // wave-uniform last active kt
            if (kt > lim) continue;

            // S = Q K^T, kf shared across both strips
            floatx4 S[2][4];
            #pragma unroll
            for (int s = 0; s < 2; s++)
                #pragma unroll
                for (int a = 0; a < 4; a++) S[s][a] = (floatx4){0.f, 0.f, 0.f, 0.f};
            #pragma unroll
            for (int c = 0; c < 2; c++)
                #pragma unroll
                for (int a = 0; a < 4; a++) {
                    int R = a * 16 + lr;
                    short8 kf = *(const short8*)(Ksb + R * 64 + (((c * 4 + quad) ^ (lr & 7)) * 8));
                    #pragma unroll
                    for (int s = 0; s < 2; s++)
                        S[s][a] = __builtin_amdgcn_mfma_f32_16x16x32_bf16(qf[tt][s][c], kf, S[s][a], 0, 0, 0);
                }

            // causal mask, only on this wave's final active iteration
            if (kt == lim) {
                #pragma unroll
                for (int s = 0; s < 2; s++)
                    #pragma unroll
                    for (int a = 0; a < 4; a++) {
                        int col = k0 + a * 16 + lr;
                        #pragma unroll
                        for (int r = 0; r < 4; r++) {
                            int grow = qt2 * 128 + wave * 32 + s * 16 + quad * 4 + r;
                            if (col > grow) S[s][a][r] = -INFINITY;
                        }
                    }
            }

            // P = 2^s, accumulate row-sums, bf16 into per-strip LDS buffers
            #pragma unroll
            for (int s = 0; s < 2; s++)
                #pragma unroll
                for (int a = 0; a < 4; a++)
                    #pragma unroll
                    for (int r = 0; r < 4; r++) {
                        float p = __builtin_amdgcn_exp2f(S[s][a][r]);
                        ls[tt][s][r] += p;
                        Ps[wave][s][(quad * 4 + r) * 72 + a * 16 + lr] = f2b_fast(p);
                    }

            // P A-fragments (both strips live for vf sharing)
            short8 pa[2][2];
            #pragma unroll
            for (int s = 0; s < 2; s++)
                #pragma unroll
                for (int c = 0; c < 2; c++)
                    pa[s][c] = *(const short8*)(Ps[wave][s] + lr * 72 + c * 32 + quad * 8);

            // O += P V, vf shared across both strips
            #pragma unroll
            for (int c = 0; c < 2; c++)
                #pragma unroll
                for (int d = 0; d < 4; d++) {
                    int R = d * 16 + lr;
                    short8 vf = *(const short8*)(Vsb + R * 64 + (((c * 4 + quad) ^ (lr & 7)) * 8));
                    #pragma unroll
                    for (int s = 0; s < 2; s++)
                        O[tt][s][d] = __builtin_amdgcn_mfma_f32_16x16x32_bf16(pa[s][c], vf, O[tt][s][d], 0, 0, 0);
                }
        }

        // next tile landed + all waves done reading this buffer
        asm volatile("s_waitcnt vmcnt(0)" ::: "memory");
        __builtin_amdgcn_s_barrier();
    }
#undef STAGE_KV

    // final row-sum reduction (over lr lanes) + normalize + store
    #pragma unroll
    for (int tt = 0; tt < 2; tt++)
        #pragma unroll
        for (int s = 0; s < 2; s++)
            #pragma unroll
            for (int r = 0; r < 4; r++) {
                float sm = ls[tt][s][r];
                sm += __shfl_xor(sm, 1);
                sm += __shfl_xor(sm, 2);
                sm += __shfl_xor(sm, 4);
                sm += __shfl_xor(sm, 8);
                float inv = 1.0f / sm;
                size_t base = ((size_t)(b * 2048 + qt_[tt] * 128 + wave * 32 + s * 16 + quad * 4 + r)) * 1024
                              + h * 64 + lr;
                #pragma unroll
                for (int d = 0; d < 4; d++)
                    sa[base + d * 16] = f2b(O[tt][s][d][r] * inv);
            }
}

// ---------------------------------------------------------------------------
// Kernel: output projection, 128x256 tile, same pipelined main loop.
// grid 64x4 = 256 blocks = 1 clean round. Direct fp32 stores + bias.
// ---------------------------------------------------------------------------
__global__ __launch_bounds__(512, 2) void gemm_proj(
    const unsigned short* __restrict__ A,    // sa16 [8192][1024]
    const unsigned short* __restrict__ Bt,   // Wpt [1024][1024] out-major
    const float* __restrict__ bp,            // [1024]
    float* __restrict__ out)                 // [8192][1024] fp32
{
    __shared__ unsigned short smem[73728];   // 144KB

    const int mt = blockIdx.x;               // 0..63
    const int ct = blockIdx.y;               // 0..3
    const int row0 = mt * 128, col0 = ct * 256;

    floatx4 acc[4][4];
    mainloop_128x256(A, Bt, smem, row0, col0, acc);

    const int t = threadIdx.x;
    const int lane = t & 63, wave = t >> 6;
    const int lr = lane & 15, quad = lane >> 4;
    const int wr = wave >> 2, wc = wave & 3;

    float bias[4]; int cols[4];
    #pragma unroll
    for (int n = 0; n < 4; n++) {
        cols[n] = col0 + wc * 64 + n * 16 + lr;
        bias[n] = bp[cols[n]];
    }
    #pragma unroll
    for (int a = 0; a < 4; a++) {
        #pragma unroll
        for (int n = 0; n < 4; n++) {
            #pragma unroll
            for (int r = 0; r < 4; r++) {
                int m = row0 + wr * 64 + a * 16 + quad * 4 + r;
                out[(size_t)m * 1024 + cols[n]] = acc[a][n][r] + bias[n];
            }
        }
    }
}

extern "C" void kernel_launch(void* const* d_in, const int* in_sizes, int n_in,
                              void* d_out, int out_size, void* d_ws, size_t ws_size,
                              hipStream_t stream) {
    const float* x  = (const float*)d_in[0];   // [4,2048,1024]
    const float* Wk = (const float*)d_in[1];   // [16,1024,192]
    const float* bk = (const float*)d_in[2];   // [16,192]
    const float* Wp = (const float*)d_in[3];   // [1024,1024]
    const float* bp = (const float*)d_in[4];   // [1024]
    float* out = (float*)d_out;                // [4,2048,1024]

    unsigned short* Kb16 = (unsigned short*)d_ws;   // [bh][2048][64]
    unsigned short* Qb16 = Kb16 + NKV;              // pre-scaled by 0.125*log2e
    unsigned short* Vt16 = Qb16 + NKV;              // [bh][64][2048]
    unsigned short* sa16 = Vt16 + NKV;              // [8192][1024]
    unsigned short* x16  = sa16 + 8388608ull;       // [8192][1024]
    unsigned short* Wt   = x16  + 8388608ull;       // [3072][1024] permuted
    unsigned short* Wpt  = Wt   + 3145728ull;       // [1024][1024]

    convert_x<<<4096, 256, 0, stream>>>(x, x16);
    prep_wkqv<<<dim3(32, 6, 16), 256, 0, stream>>>(Wk, Wt);
    transpose_w<<<dim3(32, 32, 1), 256, 0, stream>>>(Wp, Wpt, 1024, 1024);
    gemm_kqv<<<dim3(64, 12), 512, 0, stream>>>(x16, Wt, bk, Kb16, Qb16, Vt16);
    attn_mfma<<<dim3(64, 8), 256, 0, stream>>>(Kb16, Qb16, Vt16, sa16);
    gemm_proj<<<dim3(64, 4), 512, 0, stream>>>(sa16, Wpt, bp, out);
}

// Round 6
// 230.851 us; speedup vs baseline: 1.0307x; 1.0208x over previous
//
#include <hip/hip_runtime.h>
#include <math.h>

// Problem constants
#define EMBED   1024
#define NHEADS  16
#define HD      64
#define BATCH   4
#define SEQ     2048
#define MROWS   (BATCH*SEQ)          // 8192
#define NKV     8388608ull           // B*H*N*64 floats per K/Q/V buffer

typedef short short8 __attribute__((ext_vector_type(8)));
typedef float floatx4 __attribute__((ext_vector_type(4)));

__device__ __forceinline__ unsigned short f2b(float f) {
    union { float f; unsigned u; } v; v.f = f;
    unsigned r = v.u + 0x7FFFu + ((v.u >> 16) & 1u);   // RN-even bf16
    return (unsigned short)(r >> 16);
}
__device__ __forceinline__ unsigned short f2b_fast(float f) {
    union { float f; unsigned u; } v; v.f = f;
    return (unsigned short)((v.u + 0x8000u) >> 16);    // round-half-up (2 ops)
}

// async global->LDS, 16B per lane; LDS dest = wave-uniform base + lane*16
#define GLDS16(gp, lp) __builtin_amdgcn_global_load_lds( \
    (const __attribute__((address_space(1))) unsigned int*)(gp), \
    (__attribute__((address_space(3))) unsigned int*)(lp), 16, 0, 0)

// ---------------------------------------------------------------------------
// Merged pre-pass kernel (single launch):
//   blocks [0,4096):    x fp32 -> bf16
//   blocks [4096,7168): W_kqv -> Wt' [3072][1024] permuted out-major
//   blocks [7168,8192): W_proj -> Wpt [1024][1024] transposed
// ---------------------------------------------------------------------------
__global__ __launch_bounds__(256) void prepass(
    const float* __restrict__ x,  unsigned short* __restrict__ x16,
    const float* __restrict__ Wk, unsigned short* __restrict__ Wt,
    const float* __restrict__ Wp, unsigned short* __restrict__ Wpt)
{
    __shared__ float tile[32][33];
    const int bid = blockIdx.x;

    if (bid < 4096) {                        // ---- convert_x
        size_t idx = ((size_t)bid * 256 + threadIdx.x) * 8;
        float4 a = *(const float4*)(x + idx);
        float4 b = *(const float4*)(x + idx + 4);
        ushort4 u0, u1;
        u0.x = f2b(a.x); u0.y = f2b(a.y); u0.z = f2b(a.z); u0.w = f2b(a.w);
        u1.x = f2b(b.x); u1.y = f2b(b.y); u1.z = f2b(b.z); u1.w = f2b(b.w);
        *(ushort4*)(x16 + idx) = u0;
        *(ushort4*)(x16 + idx + 4) = u1;
        return;
    }

    const int tx = threadIdx.x & 31, ty = threadIdx.x >> 5;
    if (bid < 7168) {                        // ---- prep_wkqv
        const int bb = bid - 4096;           // linear of (32,6,16)
        const int h = bb / 192;
        const int k0 = (bb & 31) * 32, e0 = ((bb >> 5) % 6) * 32;
        const float* inh = Wk + (size_t)h * 1024 * 192;
        #pragma unroll
        for (int i = 0; i < 4; i++)
            tile[ty + i * 8][tx] = inh[(size_t)(k0 + ty + i * 8) * 192 + e0 + tx];
        __syncthreads();
        #pragma unroll
        for (int i = 0; i < 4; i++) {
            int e = e0 + ty + i * 8;
            int cp = (e >> 6) * 1024 + h * 64 + (e & 63);
            Wt[(size_t)cp * 1024 + k0 + tx] = f2b(tile[tx][ty + i * 8]);
        }
        return;
    }

    {                                        // ---- transpose_w (1024x1024)
        const int bb = bid - 7168;           // linear of (32,32)
        const int r0 = (bb & 31) * 32, c0 = (bb >> 5) * 32;
        #pragma unroll
        for (int i = 0; i < 4; i++)
            tile[ty + i * 8][tx] = Wp[(size_t)(r0 + ty + i * 8) * 1024 + c0 + tx];
        __syncthreads();
        #pragma unroll
        for (int i = 0; i < 4; i++)
            Wpt[(size_t)(c0 + ty + i * 8) * 1024 + r0 + tx] = f2b(tile[tx][ty + i * 8]);
    }
}

// ---------------------------------------------------------------------------
// Shared main loop: 128x256 output tile, 512 threads / 8 waves (2M x 4N),
// wave tile 64x64, acc[4][4]. BK=64. TRIPLE-buffered A and B, ONE barrier
// per K-tile (triple buffering makes the staged slot's last readers complete
// before the previous barrier). Per iter: {16 ds_read; stage A(j+2)+B(j+2);
// lgkmcnt(0); setprio(1); 32 MFMA; setprio(0); vmcnt(6); barrier}.
// LDS 144KB: 3 x A[128][64] + 3 x B[256][64].
// ---------------------------------------------------------------------------
__device__ __forceinline__ void mainloop_128x256(
    const unsigned short* __restrict__ Ag,   // [8192][1024] bf16
    const unsigned short* __restrict__ Bg,   // [*][1024] bf16 out-major
    unsigned short* smem,                    // 73728 shorts (144KB)
    int row0, int col0, floatx4 (&acc)[4][4])
{
    const int t = threadIdx.x;
    const int wave = t >> 6, lane = t & 63;
    const int lr = lane & 15, quad = lane >> 4;
    const int wr = wave >> 2, wc = wave & 3;
    const int swz8 = ((lane & 7) ^ ((lane >> 3) & 7)) * 8;  // stage src swizzle
    const int c0 = (quad ^ (lr & 7)) * 8;        // kc0 fragment chunk (shorts)
    const int c1 = ((4 + quad) ^ (lr & 7)) * 8;  // kc1

    #pragma unroll
    for (int m = 0; m < 4; m++)
        #pragma unroll
        for (int n = 0; n < 4; n++) acc[m][n] = (floatx4){0.f, 0.f, 0.f, 0.f};

#define STG(G, R0, KC, L) do { \
    _Pragma("unroll") \
    for (int i_ = 0; i_ < 2; i_++) { \
        int rl_ = i_ * 64 + wave * 8 + (lane >> 3); \
        GLDS16((G) + (size_t)((R0) + rl_) * 1024 + (KC) + swz8, \
               (L) + rl_ * 64 + (lane & 7) * 8); \
    } } while (0)

    // static buffer slots
    unsigned short* const a0 = smem;                 // A: 8192 shorts each
    unsigned short* const a1 = smem + 8192;
    unsigned short* const a2 = smem + 16384;
    unsigned short* const b0 = smem + 24576;         // B: 16384 shorts each
    unsigned short* const b1 = smem + 24576 + 16384;
    unsigned short* const b2 = smem + 24576 + 32768;

    // one K-tile: read slot AR/BR, stage K-tile J+2 into AT/BT
#define KTILE(J, AR, BR, AT, BT) do { \
    const unsigned short* pA_ = (AR) + (wr * 64 + lr) * 64; \
    const unsigned short* pB_ = (BR) + (wc * 64 + lr) * 64; \
    short8 af0[4], af1[4], b0f[4], b1f[4]; \
    _Pragma("unroll") \
    for (int m = 0; m < 4; m++) { \
        af0[m] = *(const short8*)(pA_ + m * 1024 + c0); \
        af1[m] = *(const short8*)(pA_ + m * 1024 + c1); \
    } \
    _Pragma("unroll") \
    for (int n = 0; n < 4; n++) { \
        b0f[n] = *(const short8*)(pB_ + n * 1024 + c0); \
        b1f[n] = *(const short8*)(pB_ + n * 1024 + c1); \
    } \
    if ((J) < 14) { \
        STG(Ag, row0,       ((J) + 2) * 64, (AT)); \
        STG(Bg, col0,       ((J) + 2) * 64, (BT)); \
        STG(Bg, col0 + 128, ((J) + 2) * 64, (BT) + 8192); \
    } \
    asm volatile("s_waitcnt lgkmcnt(0)" ::: "memory"); \
    __builtin_amdgcn_s_setprio(1); \
    _Pragma("unroll") \
    for (int m = 0; m < 4; m++) \
        _Pragma("unroll") \
        for (int n = 0; n < 4; n++) \
            acc[m][n] = __builtin_amdgcn_mfma_f32_16x16x32_bf16(af0[m], b0f[n], acc[m][n], 0, 0, 0); \
    _Pragma("unroll") \
    for (int m = 0; m < 4; m++) \
        _Pragma("unroll") \
        for (int n = 0; n < 4; n++) \
            acc[m][n] = __builtin_amdgcn_mfma_f32_16x16x32_bf16(af1[m], b1f[n], acc[m][n], 0, 0, 0); \
    __builtin_amdgcn_s_setprio(0); \
    if ((J) < 14)       { asm volatile("s_waitcnt vmcnt(6)" ::: "memory"); } \
    else if ((J) == 14) { asm volatile("s_waitcnt vmcnt(0)" ::: "memory"); } \
    __builtin_amdgcn_s_barrier(); \
} while (0)

    // ---- prologue: A0,B0,A1,B1 in flight (12 loads)
    STG(Ag, row0,       0,  a0);
    STG(Bg, col0,       0,  b0);
    STG(Bg, col0 + 128, 0,  b0 + 8192);
    STG(Ag, row0,       64, a1);
    STG(Bg, col0,       64, b1);
    STG(Bg, col0 + 128, 64, b1 + 8192);
    asm volatile("s_waitcnt vmcnt(6)" ::: "memory");   // A0,B0 landed; A1,B1 in flight
    __builtin_amdgcn_s_barrier();

    // 16 K-tiles: 5 x 3 + 1, static slot rotation (read j%3, stage (j+2)%3)
    for (int j0 = 0; j0 < 15; j0 += 3) {
        KTILE(j0,     a0, b0, a2, b2);
        KTILE(j0 + 1, a1, b1, a0, b0);
        KTILE(j0 + 2, a2, b2, a1, b1);
    }
    KTILE(15, a0, b0, a2, b2);
#undef KTILE
#undef STG
}

// ---------------------------------------------------------------------------
// Kernel: KQV projection, 128x256 tile. grid 64x12 = 768 blocks = 3 clean
// rounds at 1 block/CU (144KB LDS).
// ---------------------------------------------------------------------------
__global__ __launch_bounds__(512, 2) void gemm_kqv(
    const unsigned short* __restrict__ A,    // x16 [8192][1024]
    const unsigned short* __restrict__ Bt,   // Wt' [3072][1024] permuted
    const float* __restrict__ bk,            // [16][192] original bias
    unsigned short* __restrict__ Kb16,
    unsigned short* __restrict__ Qb16,
    unsigned short* __restrict__ Vt16)
{
    __shared__ unsigned short smem[73728];   // 144KB

    const int mt = blockIdx.x;               // 0..63
    const int ct = blockIdx.y;               // 0..11
    const int row0 = mt * 128, col0 = ct * 256;

    floatx4 acc[4][4];
    mainloop_128x256(A, Bt, smem, row0, col0, acc);

    const int t = threadIdx.x;
    const int wave = t >> 6, lane = t & 63;
    const int lr = lane & 15, quad = lane >> 4;
    const int wr = wave >> 2, wc = wave & 3;

    // ---- epilogue: per-wave 64x64 sub-tile = one head's 64 dims
    unsigned short* W = smem + wave * 4096;  // 8KB region, wave-private
    const int sec = ct >> 2;                 // 0=K,1=Q,2=V (block-uniform)
    const int h = ((ct & 3) << 2) + wc;      // head owned by this wave
    const int bidx = row0 >> 11;
    const int rbase = (row0 & 2047) + wr * 64;

    float bias[4];
    #pragma unroll
    for (int n = 0; n < 4; n++) bias[n] = bk[h * 192 + sec * 64 + n * 16 + lr];

    if (sec < 2) {
        const float scl = (sec == 1) ? (0.125f * 1.44269504089f) : 1.0f;
        #pragma unroll
        for (int m = 0; m < 4; m++)
            #pragma unroll
            for (int n = 0; n < 4; n++) {
                int es = (n * 16 + lr) ^ (quad << 4);   // bank swizzle
                #pragma unroll
                for (int r = 0; r < 4; r++)
                    W[(m * 16 + quad * 4 + r) * 64 + es] = f2b((acc[m][n][r] + bias[n]) * scl);
            }
        __syncthreads();
        unsigned short* dst = ((sec == 0) ? Kb16 : Qb16)
                              + ((size_t)(bidx * 16 + h) * 2048 + rbase) * 64;
        const int rrow = lane >> 3, chunk = lane & 7;
        #pragma unroll
        for (int p = 0; p < 8; p++) {
            int row = p * 8 + rrow;
            int ch = chunk ^ (((row >> 2) & 3) << 1);   // de-swizzle
            *(float4*)(dst + (size_t)row * 64 + chunk * 8) =
                *(const float4*)(W + row * 64 + ch * 8);
        }
    } else {
        #pragma unroll
        for (int m = 0; m < 4; m++)
            #pragma unroll
            for (int n = 0; n < 4; n++) {
                int e = n * 16 + lr;
                ushort4 pk;
                pk.x = f2b(acc[m][n][0] + bias[n]);
                pk.y = f2b(acc[m][n][1] + bias[n]);
                pk.z = f2b(acc[m][n][2] + bias[n]);
                pk.w = f2b(acc[m][n][3] + bias[n]);
                int mp = m ^ (lr & 3);                  // bank swizzle on m-bits
                *(ushort4*)(W + e * 64 + mp * 16 + quad * 4) = pk;
            }
        __syncthreads();
        unsigned short* dstV = Vt16 + (size_t)(bidx * 16 + h) * 64 * 2048 + rbase;
        const int ev = lane >> 3, chunkR = lane & 7;
        #pragma unroll
        for (int p = 0; p < 8; p++) {
            int e = p * 8 + ev;
            int ch = chunkR ^ ((e & 3) << 1);           // de-swizzle
            *(float4*)(dstV + (size_t)e * 2048 + chunkR * 8) =
                *(const float4*)(W + e * 64 + ch * 8);
        }
    }
}

// ---------------------------------------------------------------------------
// Kernel: flash-style causal attention, bf16 MFMA.
// This round: ONE 128-row q-tile per block; grid dim3(64 bh, 16) with
// qt = 15 - blockIdx.y (largest blocks dispatched first -> LPT backfill).
// 3 blocks/CU resident (launch_bounds(256,3), LDS 50KB) vs 2 before --
// the serial QK^T -> softmax(VALU) -> Ps -> PV chain now overlaps across
// 3 independent blocks per CU. bh stays blockIdx.x for XCD L2 locality.
// ---------------------------------------------------------------------------
__global__ __launch_bounds__(256, 3) void attn_mfma(
    const unsigned short* __restrict__ Kb,   // [bh][2048][64]
    const unsigned short* __restrict__ Qb,   // [bh][2048][64], pre-scaled
    const unsigned short* __restrict__ Vt,   // [bh][64][2048]
    unsigned short* __restrict__ sa)         // [8192][1024] bf16
{
    const int bh = blockIdx.x;               // 0..63  (XCD = bh & 7)
    const int qt = 15 - blockIdx.y;          // largest-first dispatch
    const int b = bh >> 4, h = bh & 15;
    const int wave = threadIdx.x >> 6;
    const int lane = threadIdx.x & 63;
    const int lr = lane & 15, quad = lane >> 4;

    __shared__ unsigned short Ks[2][64 * 64];  // double-buffered, swizzled
    __shared__ unsigned short Vs[2][64 * 64];
    __shared__ unsigned short Ps[4][2][16 * 72]; // per-wave per-strip P

    const unsigned short* Kbh = Kb + (size_t)bh * 2048 * 64;
    const unsigned short* Vbh = Vt + (size_t)bh * 64 * 2048;
    const unsigned short* Qbh = Qb + (size_t)bh * 2048 * 64;

    // Q A-fragments: 2 strips x 2 K-chunks
    short8 qf[2][2];
    #pragma unroll
    for (int s = 0; s < 2; s++) {
        const unsigned short* qp = Qbh +
            (size_t)(qt * 128 + wave * 32 + s * 16 + lr) * 64 + quad * 8;
        qf[s][0] = *(const short8*)(qp);
        qf[s][1] = *(const short8*)(qp + 32);
    }

    floatx4 O[2][4];
    float ls[2][4];
    #pragma unroll
    for (int s = 0; s < 2; s++) {
        #pragma unroll
        for (int d = 0; d < 4; d++) O[s][d] = (floatx4){0.f, 0.f, 0.f, 0.f};
        #pragma unroll
        for (int r = 0; r < 4; r++) ls[s][r] = 0.f;
    }

    const int r_local = lane >> 3, cc = lane & 7;
    const int swz = cc ^ r_local;            // data chunk this lane stages
    const int whalf = wave >> 1;             // 0: rows 0..63, 1: rows 64..127

    // stage K/V tile kt into buffer bsel (4 GLDS per wave)
#define STAGE_KV(KT, BSEL) do { \
    const int k0_ = (KT) * 64; \
    _Pragma("unroll") \
    for (int j_ = 0; j_ < 2; j_++) { \
        int R_ = wave * 16 + j_ * 8 + r_local; \
        GLDS16(Kbh + (size_t)(k0_ + R_) * 64 + swz * 8, \
               &Ks[BSEL][0] + (wave * 16 + j_ * 8) * 64 + lane * 8); \
        GLDS16(Vbh + (size_t)R_ * 2048 + k0_ + swz * 8, \
               &Vs[BSEL][0] + (wave * 16 + j_ * 8) * 64 + lane * 8); \
    } } while (0)

    const int ktmax = 2 * qt + 1;
    const int lim = 2 * qt + whalf;          // wave-uniform last active kt

    // prologue: stage kt=0 into buffer 0; wait (also covers qf loads)
    STAGE_KV(0, 0);
    asm volatile("s_waitcnt vmcnt(0)" ::: "memory");
    __builtin_amdgcn_s_barrier();

    for (int kt = 0; kt <= ktmax; kt++) {
        const int buf = kt & 1;
        const unsigned short* Ksb = &Ks[buf][0];
        const unsigned short* Vsb = &Vs[buf][0];
        const int k0 = kt * 64;

        // stage next tile into the other buffer (its readers finished at the
        // barrier that closed iteration kt-1)
        if (kt < ktmax) {
            if (buf) STAGE_KV(kt + 1, 0);
            else     STAGE_KV(kt + 1, 1);
        }

        if (kt <= lim) {
            // S = Q K^T, kf shared across both strips
            floatx4 S[2][4];
            #pragma unroll
            for (int s = 0; s < 2; s++)
                #pragma unroll
                for (int a = 0; a < 4; a++) S[s][a] = (floatx4){0.f, 0.f, 0.f, 0.f};
            #pragma unroll
            for (int c = 0; c < 2; c++)
                #pragma unroll
                for (int a = 0; a < 4; a++) {
                    int R = a * 16 + lr;
                    short8 kf = *(const short8*)(Ksb + R * 64 + (((c * 4 + quad) ^ (lr & 7)) * 8));
                    #pragma unroll
                    for (int s = 0; s < 2; s++)
                        S[s][a] = __builtin_amdgcn_mfma_f32_16x16x32_bf16(qf[s][c], kf, S[s][a], 0, 0, 0);
                }

            // causal mask, only on this wave's final active iteration
            if (kt == lim) {
                #pragma unroll
                for (int s = 0; s < 2; s++)
                    #pragma unroll
                    for (int a = 0; a < 4; a++) {
                        int col = k0 + a * 16 + lr;
                        #pragma unroll
                        for (int r = 0; r < 4; r++) {
                            int grow = qt * 128 + wave * 32 + s * 16 + quad * 4 + r;
                            if (col > grow) S[s][a][r] = -INFINITY;
                        }
                    }
            }

            // P = 2^s, accumulate row-sums, bf16 into per-strip LDS buffers
            #pragma unroll
            for (int s = 0; s < 2; s++)
                #pragma unroll
                for (int a = 0; a < 4; a++)
                    #pragma unroll
                    for (int r = 0; r < 4; r++) {
                        float p = __builtin_amdgcn_exp2f(S[s][a][r]);
                        ls[s][r] += p;
                        Ps[wave][s][(quad * 4 + r) * 72 + a * 16 + lr] = f2b_fast(p);
                    }

            // P A-fragments (both strips live for vf sharing)
            short8 pa[2][2];
            #pragma unroll
            for (int s = 0; s < 2; s++)
                #pragma unroll
                for (int c = 0; c < 2; c++)
                    pa[s][c] = *(const short8*)(Ps[wave][s] + lr * 72 + c * 32 + quad * 8);

            // O += P V, vf shared across both strips
            #pragma unroll
            for (int c = 0; c < 2; c++)
                #pragma unroll
                for (int d = 0; d < 4; d++) {
                    int R = d * 16 + lr;
                    short8 vf = *(const short8*)(Vsb + R * 64 + (((c * 4 + quad) ^ (lr & 7)) * 8));
                    #pragma unroll
                    for (int s = 0; s < 2; s++)
                        O[s][d] = __builtin_amdgcn_mfma_f32_16x16x32_bf16(pa[s][c], vf, O[s][d], 0, 0, 0);
                }
        }

        // next tile landed + all waves done reading this buffer
        asm volatile("s_waitcnt vmcnt(0)" ::: "memory");
        __builtin_amdgcn_s_barrier();
    }
#undef STAGE_KV

    // final row-sum reduction (over lr lanes) + normalize + store
    #pragma unroll
    for (int s = 0; s < 2; s++)
        #pragma unroll
        for (int r = 0; r < 4; r++) {
            float sm = ls[s][r];
            sm += __shfl_xor(sm, 1);
            sm += __shfl_xor(sm, 2);
            sm += __shfl_xor(sm, 4);
            sm += __shfl_xor(sm, 8);
            float inv = 1.0f / sm;
            size_t base = ((size_t)(b * 2048 + qt * 128 + wave * 32 + s * 16 + quad * 4 + r)) * 1024
                          + h * 64 + lr;
            #pragma unroll
            for (int d = 0; d < 4; d++)
                sa[base + d * 16] = f2b(O[s][d][r] * inv);
        }
}

// ---------------------------------------------------------------------------
// Kernel: output projection, 128x256 tile, same pipelined main loop.
// grid 64x4 = 256 blocks = 1 clean round. Direct fp32 stores + bias.
// ---------------------------------------------------------------------------
__global__ __launch_bounds__(512, 2) void gemm_proj(
    const unsigned short* __restrict__ A,    // sa16 [8192][1024]
    const unsigned short* __restrict__ Bt,   // Wpt [1024][1024] out-major
    const float* __restrict__ bp,            // [1024]
    float* __restrict__ out)                 // [8192][1024] fp32
{
    __shared__ unsigned short smem[73728];   // 144KB

    const int mt = blockIdx.x;               // 0..63
    const int ct = blockIdx.y;               // 0..3
    const int row0 = mt * 128, col0 = ct * 256;

    floatx4 acc[4][4];
    mainloop_128x256(A, Bt, smem, row0, col0, acc);

    const int t = threadIdx.x;
    const int lane = t & 63, wave = t >> 6;
    const int lr = lane & 15, quad = lane >> 4;
    const int wr = wave >> 2, wc = wave & 3;

    float bias[4]; int cols[4];
    #pragma unroll
    for (int n = 0; n < 4; n++) {
        cols[n] = col0 + wc * 64 + n * 16 + lr;
        bias[n] = bp[cols[n]];
    }
    #pragma unroll
    for (int a = 0; a < 4; a++) {
        #pragma unroll
        for (int n = 0; n < 4; n++) {
            #pragma unroll
            for (int r = 0; r < 4; r++) {
                int m = row0 + wr * 64 + a * 16 + quad * 4 + r;
                out[(size_t)m * 1024 + cols[n]] = acc[a][n][r] + bias[n];
            }
        }
    }
}

extern "C" void kernel_launch(void* const* d_in, const int* in_sizes, int n_in,
                              void* d_out, int out_size, void* d_ws, size_t ws_size,
                              hipStream_t stream) {
    const float* x  = (const float*)d_in[0];   // [4,2048,1024]
    const float* Wk = (const float*)d_in[1];   // [16,1024,192]
    const float* bk = (const float*)d_in[2];   // [16,192]
    const float* Wp = (const float*)d_in[3];   // [1024,1024]
    const float* bp = (const float*)d_in[4];   // [1024]
    float* out = (float*)d_out;                // [4,2048,1024]

    unsigned short* Kb16 = (unsigned short*)d_ws;   // [bh][2048][64]
    unsigned short* Qb16 = Kb16 + NKV;              // pre-scaled by 0.125*log2e
    unsigned short* Vt16 = Qb16 + NKV;              // [bh][64][2048]
    unsigned short* sa16 = Vt16 + NKV;              // [8192][1024]
    unsigned short* x16  = sa16 + 8388608ull;       // [8192][1024]
    unsigned short* Wt   = x16  + 8388608ull;       // [3072][1024] permuted
    unsigned short* Wpt  = Wt   + 3145728ull;       // [1024][1024]

    prepass<<<8192, 256, 0, stream>>>(x, x16, Wk, Wt, Wp, Wpt);
    gemm_kqv<<<dim3(64, 12), 512, 0, stream>>>(x16, Wt, bk, Kb16, Qb16, Vt16);
    attn_mfma<<<dim3(64, 16), 256, 0, stream>>>(Kb16, Qb16, Vt16, sa16);
    gemm_proj<<<dim3(64, 4), 512, 0, stream>>>(sa16, Wpt, bp, out);
}

// Round 9
// 213.919 us; speedup vs baseline: 1.1122x; 1.0792x over previous
//
#include <hip/hip_runtime.h>
#include <math.h>

// Problem constants
#define EMBED   1024
#define NHEADS  16
#define HD      64
#define BATCH   4
#define SEQ     2048
#define MROWS   (BATCH*SEQ)          // 8192
#define NKV     8388608ull           // B*H*N*64 floats per K/Q/V buffer

typedef short short8 __attribute__((ext_vector_type(8)));
typedef float floatx4 __attribute__((ext_vector_type(4)));

__device__ __forceinline__ unsigned short f2b(float f) {
    union { float f; unsigned u; } v; v.f = f;
    unsigned r = v.u + 0x7FFFu + ((v.u >> 16) & 1u);   // RN-even bf16
    return (unsigned short)(r >> 16);
}
__device__ __forceinline__ unsigned short f2b_fast(float f) {
    union { float f; unsigned u; } v; v.f = f;
    return (unsigned short)((v.u + 0x8000u) >> 16);    // round-half-up (2 ops)
}

// async global->LDS, 16B per lane; LDS dest = wave-uniform base + lane*16
#define GLDS16(gp, lp) __builtin_amdgcn_global_load_lds( \
    (const __attribute__((address_space(1))) unsigned int*)(gp), \
    (__attribute__((address_space(3))) unsigned int*)(lp), 16, 0, 0)

// ---------------------------------------------------------------------------
// Merged pre-pass kernel (single launch):
//   blocks [0,4096):    x fp32 -> bf16
//   blocks [4096,7168): W_kqv -> Wt' [3072][1024] permuted out-major
//   blocks [7168,8192): W_proj -> Wpt [1024][1024] transposed
// ---------------------------------------------------------------------------
__global__ __launch_bounds__(256) void prepass(
    const float* __restrict__ x,  unsigned short* __restrict__ x16,
    const float* __restrict__ Wk, unsigned short* __restrict__ Wt,
    const float* __restrict__ Wp, unsigned short* __restrict__ Wpt)
{
    __shared__ float tile[32][33];
    const int bid = blockIdx.x;

    if (bid < 4096) {                        // ---- convert_x
        size_t idx = ((size_t)bid * 256 + threadIdx.x) * 8;
        float4 a = *(const float4*)(x + idx);
        float4 b = *(const float4*)(x + idx + 4);
        ushort4 u0, u1;
        u0.x = f2b(a.x); u0.y = f2b(a.y); u0.z = f2b(a.z); u0.w = f2b(a.w);
        u1.x = f2b(b.x); u1.y = f2b(b.y); u1.z = f2b(b.z); u1.w = f2b(b.w);
        *(ushort4*)(x16 + idx) = u0;
        *(ushort4*)(x16 + idx + 4) = u1;
        return;
    }

    const int tx = threadIdx.x & 31, ty = threadIdx.x >> 5;
    if (bid < 7168) {                        // ---- prep_wkqv
        const int bb = bid - 4096;           // linear of (32,6,16)
        const int h = bb / 192;
        const int k0 = (bb & 31) * 32, e0 = ((bb >> 5) % 6) * 32;
        const float* inh = Wk + (size_t)h * 1024 * 192;
        #pragma unroll
        for (int i = 0; i < 4; i++)
            tile[ty + i * 8][tx] = inh[(size_t)(k0 + ty + i * 8) * 192 + e0 + tx];
        __syncthreads();
        #pragma unroll
        for (int i = 0; i < 4; i++) {
            int e = e0 + ty + i * 8;
            int cp = (e >> 6) * 1024 + h * 64 + (e & 63);
            Wt[(size_t)cp * 1024 + k0 + tx] = f2b(tile[tx][ty + i * 8]);
        }
        return;
    }

    {                                        // ---- transpose_w (1024x1024)
        const int bb = bid - 7168;           // linear of (32,32)
        const int r0 = (bb & 31) * 32, c0 = (bb >> 5) * 32;
        #pragma unroll
        for (int i = 0; i < 4; i++)
            tile[ty + i * 8][tx] = Wp[(size_t)(r0 + ty + i * 8) * 1024 + c0 + tx];
        __syncthreads();
        #pragma unroll
        for (int i = 0; i < 4; i++)
            Wpt[(size_t)(c0 + ty + i * 8) * 1024 + r0 + tx] = f2b(tile[tx][ty + i * 8]);
    }
}

// ---------------------------------------------------------------------------
// Shared main loop: 128x256 output tile, 512 threads / 8 waves (2M x 4N),
// wave tile 64x64, acc[4][4]. BK=64. TRIPLE-buffered A and B, ONE barrier
// per K-tile. The explicit lgkmcnt(0)+"memory" between staging and the MFMA
// cluster stays: it is the LDS-read drain making cross-wave slot reuse safe
// across the single barrier AND the compiler memory fence pinning ds_reads
// inside their phase. vmcnt(6) once per K-tile.
// LDS 144KB: 3 x A[128][64] + 3 x B[256][64].
// ---------------------------------------------------------------------------
__device__ __forceinline__ void mainloop_128x256(
    const unsigned short* __restrict__ Ag,   // [8192][1024] bf16
    const unsigned short* __restrict__ Bg,   // [*][1024] bf16 out-major
    unsigned short* smem,                    // 73728 shorts (144KB)
    int row0, int col0, floatx4 (&acc)[4][4])
{
    const int t = threadIdx.x;
    const int wave = t >> 6, lane = t & 63;
    const int lr = lane & 15, quad = lane >> 4;
    const int wr = wave >> 2, wc = wave & 3;
    const int swz8 = ((lane & 7) ^ ((lane >> 3) & 7)) * 8;  // stage src swizzle
    const int c0 = (quad ^ (lr & 7)) * 8;        // kc0 fragment chunk (shorts)
    const int c1 = ((4 + quad) ^ (lr & 7)) * 8;  // kc1

    #pragma unroll
    for (int m = 0; m < 4; m++)
        #pragma unroll
        for (int n = 0; n < 4; n++) acc[m][n] = (floatx4){0.f, 0.f, 0.f, 0.f};

#define STG(G, R0, KC, L) do { \
    _Pragma("unroll") \
    for (int i_ = 0; i_ < 2; i_++) { \
        int rl_ = i_ * 64 + wave * 8 + (lane >> 3); \
        GLDS16((G) + (size_t)((R0) + rl_) * 1024 + (KC) + swz8, \
               (L) + rl_ * 64 + (lane & 7) * 8); \
    } } while (0)

    // static buffer slots
    unsigned short* const a0 = smem;                 // A: 8192 shorts each
    unsigned short* const a1 = smem + 8192;
    unsigned short* const a2 = smem + 16384;
    unsigned short* const b0 = smem + 24576;         // B: 16384 shorts each
    unsigned short* const b1 = smem + 24576 + 16384;
    unsigned short* const b2 = smem + 24576 + 32768;

    // one K-tile: read slot AR/BR, stage K-tile J+2 into AT/BT
#define KTILE(J, AR, BR, AT, BT) do { \
    const unsigned short* pA_ = (AR) + (wr * 64 + lr) * 64; \
    const unsigned short* pB_ = (BR) + (wc * 64 + lr) * 64; \
    short8 af0[4], af1[4], b0f[4], b1f[4]; \
    _Pragma("unroll") \
    for (int m = 0; m < 4; m++) { \
        af0[m] = *(const short8*)(pA_ + m * 1024 + c0); \
        af1[m] = *(const short8*)(pA_ + m * 1024 + c1); \
    } \
    _Pragma("unroll") \
    for (int n = 0; n < 4; n++) { \
        b0f[n] = *(const short8*)(pB_ + n * 1024 + c0); \
        b1f[n] = *(const short8*)(pB_ + n * 1024 + c1); \
    } \
    if ((J) < 14) { \
        STG(Ag, row0,       ((J) + 2) * 64, (AT)); \
        STG(Bg, col0,       ((J) + 2) * 64, (BT)); \
        STG(Bg, col0 + 128, ((J) + 2) * 64, (BT) + 8192); \
    } \
    asm volatile("s_waitcnt lgkmcnt(0)" ::: "memory"); \
    __builtin_amdgcn_s_setprio(1); \
    _Pragma("unroll") \
    for (int m = 0; m < 4; m++) \
        _Pragma("unroll") \
        for (int n = 0; n < 4; n++) \
            acc[m][n] = __builtin_amdgcn_mfma_f32_16x16x32_bf16(af0[m], b0f[n], acc[m][n], 0, 0, 0); \
    _Pragma("unroll") \
    for (int m = 0; m < 4; m++) \
        _Pragma("unroll") \
        for (int n = 0; n < 4; n++) \
            acc[m][n] = __builtin_amdgcn_mfma_f32_16x16x32_bf16(af1[m], b1f[n], acc[m][n], 0, 0, 0); \
    __builtin_amdgcn_s_setprio(0); \
    if ((J) < 14)       { asm volatile("s_waitcnt vmcnt(6)" ::: "memory"); } \
    else if ((J) == 14) { asm volatile("s_waitcnt vmcnt(0)" ::: "memory"); } \
    __builtin_amdgcn_s_barrier(); \
} while (0)

    // ---- prologue: A0,B0,A1,B1 in flight (12 loads)
    STG(Ag, row0,       0,  a0);
    STG(Bg, col0,       0,  b0);
    STG(Bg, col0 + 128, 0,  b0 + 8192);
    STG(Ag, row0,       64, a1);
    STG(Bg, col0,       64, b1);
    STG(Bg, col0 + 128, 64, b1 + 8192);
    asm volatile("s_waitcnt vmcnt(6)" ::: "memory");   // A0,B0 landed; A1,B1 in flight
    __builtin_amdgcn_s_barrier();

    // 16 K-tiles: 5 x 3 + 1, static slot rotation (read j%3, stage (j+2)%3)
    for (int j0 = 0; j0 < 15; j0 += 3) {
        KTILE(j0,     a0, b0, a2, b2);
        KTILE(j0 + 1, a1, b1, a0, b0);
        KTILE(j0 + 2, a2, b2, a1, b1);
    }
    KTILE(15, a0, b0, a2, b2);
#undef KTILE
#undef STG
}

// ---------------------------------------------------------------------------
// Kernel: KQV projection, 128x256 tile. grid 64x12 = 768 blocks = 3 clean
// rounds at 1 block/CU (144KB LDS).
// ---------------------------------------------------------------------------
__global__ __launch_bounds__(512, 2) void gemm_kqv(
    const unsigned short* __restrict__ A,    // x16 [8192][1024]
    const unsigned short* __restrict__ Bt,   // Wt' [3072][1024] permuted
    const float* __restrict__ bk,            // [16][192] original bias
    unsigned short* __restrict__ Kb16,
    unsigned short* __restrict__ Qb16,
    unsigned short* __restrict__ Vt16)
{
    __shared__ unsigned short smem[73728];   // 144KB

    const int mt = blockIdx.x;               // 0..63
    const int ct = blockIdx.y;               // 0..11
    const int row0 = mt * 128, col0 = ct * 256;

    floatx4 acc[4][4];
    mainloop_128x256(A, Bt, smem, row0, col0, acc);

    const int t = threadIdx.x;
    const int wave = t >> 6, lane = t & 63;
    const int lr = lane & 15, quad = lane >> 4;
    const int wr = wave >> 2, wc = wave & 3;

    // ---- epilogue: per-wave 64x64 sub-tile = one head's 64 dims
    unsigned short* W = smem + wave * 4096;  // 8KB region, wave-private
    const int sec = ct >> 2;                 // 0=K,1=Q,2=V (block-uniform)
    const int h = ((ct & 3) << 2) + wc;      // head owned by this wave
    const int bidx = row0 >> 11;
    const int rbase = (row0 & 2047) + wr * 64;

    float bias[4];
    #pragma unroll
    for (int n = 0; n < 4; n++) bias[n] = bk[h * 192 + sec * 64 + n * 16 + lr];

    if (sec < 2) {
        const float scl = (sec == 1) ? (0.125f * 1.44269504089f) : 1.0f;
        #pragma unroll
        for (int m = 0; m < 4; m++)
            #pragma unroll
            for (int n = 0; n < 4; n++) {
                int es = (n * 16 + lr) ^ (quad << 4);   // bank swizzle
                #pragma unroll
                for (int r = 0; r < 4; r++)
                    W[(m * 16 + quad * 4 + r) * 64 + es] = f2b((acc[m][n][r] + bias[n]) * scl);
            }
        __syncthreads();
        unsigned short* dst = ((sec == 0) ? Kb16 : Qb16)
                              + ((size_t)(bidx * 16 + h) * 2048 + rbase) * 64;
        const int rrow = lane >> 3, chunk = lane & 7;
        #pragma unroll
        for (int p = 0; p < 8; p++) {
            int row = p * 8 + rrow;
            int ch = chunk ^ (((row >> 2) & 3) << 1);   // de-swizzle
            *(float4*)(dst + (size_t)row * 64 + chunk * 8) =
                *(const float4*)(W + row * 64 + ch * 8);
        }
    } else {
        #pragma unroll
        for (int m = 0; m < 4; m++)
            #pragma unroll
            for (int n = 0; n < 4; n++) {
                int e = n * 16 + lr;
                ushort4 pk;
                pk.x = f2b(acc[m][n][0] + bias[n]);
                pk.y = f2b(acc[m][n][1] + bias[n]);
                pk.z = f2b(acc[m][n][2] + bias[n]);
                pk.w = f2b(acc[m][n][3] + bias[n]);
                int mp = m ^ (lr & 3);                  // bank swizzle on m-bits
                *(ushort4*)(W + e * 64 + mp * 16 + quad * 4) = pk;
            }
        __syncthreads();
        unsigned short* dstV = Vt16 + (size_t)(bidx * 16 + h) * 64 * 2048 + rbase;
        const int ev = lane >> 3, chunkR = lane & 7;
        #pragma unroll
        for (int p = 0; p < 8; p++) {
            int e = p * 8 + ev;
            int ch = chunkR ^ ((e & 3) << 1);           // de-swizzle
            *(float4*)(dstV + (size_t)e * 2048 + chunkR * 8) =
                *(const float4*)(W + e * 64 + ch * 8);
        }
    }
}

// ---------------------------------------------------------------------------
// Kernel: flash-style causal attention, bf16 MFMA. One 128-row q-tile per
// block; grid dim3(64 bh, 16) with qt = 15 - blockIdx.y (largest-first ->
// LPT backfill). 3 blocks/CU resident (LDS 50KB). bh = blockIdx.x keeps
// XCD L2 locality. Scalar f2b_fast P-conversion (cvt_pk asm variant NaN'd
// in rounds 7-8 -- cause not isolated; do not reintroduce without .s dump).
// ---------------------------------------------------------------------------
__global__ __launch_bounds__(256, 3) void attn_mfma(
    const unsigned short* __restrict__ Kb,   // [bh][2048][64]
    const unsigned short* __restrict__ Qb,   // [bh][2048][64], pre-scaled
    const unsigned short* __restrict__ Vt,   // [bh][64][2048]
    unsigned short* __restrict__ sa)         // [8192][1024] bf16
{
    const int bh = blockIdx.x;               // 0..63  (XCD = bh & 7)
    const int qt = 15 - blockIdx.y;          // largest-first dispatch
    const int b = bh >> 4, h = bh & 15;
    const int wave = threadIdx.x >> 6;
    const int lane = threadIdx.x & 63;
    const int lr = lane & 15, quad = lane >> 4;

    __shared__ unsigned short Ks[2][64 * 64];  // double-buffered, swizzled
    __shared__ unsigned short Vs[2][64 * 64];
    __shared__ unsigned short Ps[4][2][16 * 72]; // per-wave per-strip P

    const unsigned short* Kbh = Kb + (size_t)bh * 2048 * 64;
    const unsigned short* Vbh = Vt + (size_t)bh * 64 * 2048;
    const unsigned short* Qbh = Qb + (size_t)bh * 2048 * 64;

    // Q A-fragments: 2 strips x 2 K-chunks
    short8 qf[2][2];
    #pragma unroll
    for (int s = 0; s < 2; s++) {
        const unsigned short* qp = Qbh +
            (size_t)(qt * 128 + wave * 32 + s * 16 + lr) * 64 + quad * 8;
        qf[s][0] = *(const short8*)(qp);
        qf[s][1] = *(const short8*)(qp + 32);
    }

    floatx4 O[2][4];
    float ls[2][4];
    #pragma unroll
    for (int s = 0; s < 2; s++) {
        #pragma unroll
        for (int d = 0; d < 4; d++) O[s][d] = (floatx4){0.f, 0.f, 0.f, 0.f};
        #pragma unroll
        for (int r = 0; r < 4; r++) ls[s][r] = 0.f;
    }

    const int r_local = lane >> 3, cc = lane & 7;
    const int swz = cc ^ r_local;            // data chunk this lane stages
    const int whalf = wave >> 1;             // 0: rows 0..63, 1: rows 64..127

    // stage K/V tile kt into buffer bsel (4 GLDS per wave)
#define STAGE_KV(KT, BSEL) do { \
    const int k0_ = (KT) * 64; \
    _Pragma("unroll") \
    for (int j_ = 0; j_ < 2; j_++) { \
        int R_ = wave * 16 + j_ * 8 + r_local; \
        GLDS16(Kbh + (size_t)(k0_ + R_) * 64 + swz * 8, \
               &Ks[BSEL][0] + (wave * 16 + j_ * 8) * 64 + lane * 8); \
        GLDS16(Vbh + (size_t)R_ * 2048 + k0_ + swz * 8, \
               &Vs[BSEL][0] + (wave * 16 + j_ * 8) * 64 + lane * 8); \
    } } while (0)

    const int ktmax = 2 * qt + 1;
    const int lim = 2 * qt + whalf;          // wave-uniform last active kt

    // prologue: stage kt=0 into buffer 0; wait (also covers qf loads)
    STAGE_KV(0, 0);
    asm volatile("s_waitcnt vmcnt(0)" ::: "memory");
    __builtin_amdgcn_s_barrier();

    for (int kt = 0; kt <= ktmax; kt++) {
        const int buf = kt & 1;
        const unsigned short* Ksb = &Ks[buf][0];
        const unsigned short* Vsb = &Vs[buf][0];
        const int k0 = kt * 64;

        // stage next tile into the other buffer (its readers finished at the
        // barrier that closed iteration kt-1)
        if (kt < ktmax) {
            if (buf) STAGE_KV(kt + 1, 0);
            else     STAGE_KV(kt + 1, 1);
        }

        if (kt <= lim) {
            // S = Q K^T, kf shared across both strips
            floatx4 S[2][4];
            #pragma unroll
            for (int s = 0; s < 2; s++)
                #pragma unroll
                for (int a = 0; a < 4; a++) S[s][a] = (floatx4){0.f, 0.f, 0.f, 0.f};
            #pragma unroll
            for (int c = 0; c < 2; c++)
                #pragma unroll
                for (int a = 0; a < 4; a++) {
                    int R = a * 16 + lr;
                    short8 kf = *(const short8*)(Ksb + R * 64 + (((c * 4 + quad) ^ (lr & 7)) * 8));
                    #pragma unroll
                    for (int s = 0; s < 2; s++)
                        S[s][a] = __builtin_amdgcn_mfma_f32_16x16x32_bf16(qf[s][c], kf, S[s][a], 0, 0, 0);
                }

            // causal mask, only on this wave's final active iteration
            if (kt == lim) {
                #pragma unroll
                for (int s = 0; s < 2; s++)
                    #pragma unroll
                    for (int a = 0; a < 4; a++) {
                        int col = k0 + a * 16 + lr;
                        #pragma unroll
                        for (int r = 0; r < 4; r++) {
                            int grow = qt * 128 + wave * 32 + s * 16 + quad * 4 + r;
                            if (col > grow) S[s][a][r] = -INFINITY;
                        }
                    }
            }

            // P = 2^s, accumulate row-sums, bf16 into per-strip LDS buffers
            #pragma unroll
            for (int s = 0; s < 2; s++)
                #pragma unroll
                for (int a = 0; a < 4; a++)
                    #pragma unroll
                    for (int r = 0; r < 4; r++) {
                        float p = __builtin_amdgcn_exp2f(S[s][a][r]);
                        ls[s][r] += p;
                        Ps[wave][s][(quad * 4 + r) * 72 + a * 16 + lr] = f2b_fast(p);
                    }

            // P A-fragments (both strips live for vf sharing)
            short8 pa[2][2];
            #pragma unroll
            for (int s = 0; s < 2; s++)
                #pragma unroll
                for (int c = 0; c < 2; c++)
                    pa[s][c] = *(const short8*)(Ps[wave][s] + lr * 72 + c * 32 + quad * 8);

            // O += P V, vf shared across both strips
            #pragma unroll
            for (int c = 0; c < 2; c++)
                #pragma unroll
                for (int d = 0; d < 4; d++) {
                    int R = d * 16 + lr;
                    short8 vf = *(const short8*)(Vsb + R * 64 + (((c * 4 + quad) ^ (lr & 7)) * 8));
                    #pragma unroll
                    for (int s = 0; s < 2; s++)
                        O[s][d] = __builtin_amdgcn_mfma_f32_16x16x32_bf16(pa[s][c], vf, O[s][d], 0, 0, 0);
                }
        }

        // next tile landed + all waves done reading this buffer
        asm volatile("s_waitcnt vmcnt(0)" ::: "memory");
        __builtin_amdgcn_s_barrier();
    }
#undef STAGE_KV

    // final row-sum reduction (over lr lanes) + normalize + store
    #pragma unroll
    for (int s = 0; s < 2; s++)
        #pragma unroll
        for (int r = 0; r < 4; r++) {
            float sm = ls[s][r];
            sm += __shfl_xor(sm, 1);
            sm += __shfl_xor(sm, 2);
            sm += __shfl_xor(sm, 4);
            sm += __shfl_xor(sm, 8);
            float inv = 1.0f / sm;
            size_t base = ((size_t)(b * 2048 + qt * 128 + wave * 32 + s * 16 + quad * 4 + r)) * 1024
                          + h * 64 + lr;
            #pragma unroll
            for (int d = 0; d < 4; d++)
                sa[base + d * 16] = f2b(O[s][d][r] * inv);
        }
}

// ---------------------------------------------------------------------------
// Kernel: output projection, 128x256 tile, same pipelined main loop.
// grid 64x4 = 256 blocks = 1 clean round. Direct fp32 stores + bias.
// ---------------------------------------------------------------------------
__global__ __launch_bounds__(512, 2) void gemm_proj(
    const unsigned short* __restrict__ A,    // sa16 [8192][1024]
    const unsigned short* __restrict__ Bt,   // Wpt [1024][1024] out-major
    const float* __restrict__ bp,            // [1024]
    float* __restrict__ out)                 // [8192][1024] fp32
{
    __shared__ unsigned short smem[73728];   // 144KB

    const int mt = blockIdx.x;               // 0..63
    const int ct = blockIdx.y;               // 0..3
    const int row0 = mt * 128, col0 = ct * 256;

    floatx4 acc[4][4];
    mainloop_128x256(A, Bt, smem, row0, col0, acc);

    const int t = threadIdx.x;
    const int lane = t & 63, wave = t >> 6;
    const int lr = lane & 15, quad = lane >> 4;
    const int wr = wave >> 2, wc = wave & 3;

    float bias[4]; int cols[4];
    #pragma unroll
    for (int n = 0; n < 4; n++) {
        cols[n] = col0 + wc * 64 + n * 16 + lr;
        bias[n] = bp[cols[n]];
    }
    #pragma unroll
    for (int a = 0; a < 4; a++) {
        #pragma unroll
        for (int n = 0; n < 4; n++) {
            #pragma unroll
            for (int r = 0; r < 4; r++) {
                int m = row0 + wr * 64 + a * 16 + quad * 4 + r;
                out[(size_t)m * 1024 + cols[n]] = acc[a][n][r] + bias[n];
            }
        }
    }
}

extern "C" void kernel_launch(void* const* d_in, const int* in_sizes, int n_in,
                              void* d_out, int out_size, void* d_ws, size_t ws_size,
                              hipStream_t stream) {
    const float* x  = (const float*)d_in[0];   // [4,2048,1024]
    const float* Wk = (const float*)d_in[1];   // [16,1024,192]
    const float* bk = (const float*)d_in[2];   // [16,192]
    const float* Wp = (const float*)d_in[3];   // [1024,1024]
    const float* bp = (const float*)d_in[4];   // [1024]
    float* out = (float*)d_out;                // [4,2048,1024]

    unsigned short* Kb16 = (unsigned short*)d_ws;   // [bh][2048][64]
    unsigned short* Qb16 = Kb16 + NKV;              // pre-scaled by 0.125*log2e
    unsigned short* Vt16 = Qb16 + NKV;              // [bh][64][2048]
    unsigned short* sa16 = Vt16 + NKV;              // [8192][1024]
    unsigned short* x16  = sa16 + 8388608ull;       // [8192][1024]
    unsigned short* Wt   = x16  + 8388608ull;       // [3072][1024] permuted
    unsigned short* Wpt  = Wt   + 3145728ull;       // [1024][1024]

    prepass<<<8192, 256, 0, stream>>>(x, x16, Wk, Wt, Wp, Wpt);
    gemm_kqv<<<dim3(64, 12), 512, 0, stream>>>(x16, Wt, bk, Kb16, Qb16, Vt16);
    attn_mfma<<<dim3(64, 16), 256, 0, stream>>>(Kb16, Qb16, Vt16, sa16);
    gemm_proj<<<dim3(64, 4), 512, 0, stream>>>(sa16, Wpt, bp, out);
}